// Round 5
// baseline (2225.664 us; speedup 1.0000x reference)
//
#include <hip/hip_runtime.h>
#include <math.h>

#define B_ 1024
#define T_ 15
#define E_ 128
#define H_ 1024
#define L_ 128
#define V_ 21

typedef __attribute__((ext_vector_type(8))) short bf16x8;
typedef __attribute__((ext_vector_type(4))) float f32x4;

// overflow-safe fast sigmoid / tanh (v_exp_f32 path)
__device__ __forceinline__ float sigf(float x) { return 1.0f / (1.0f + __expf(-x)); }
__device__ __forceinline__ float tanhfast(float x) {
    float t = __expf(-2.0f * fabsf(x));          // in (0,1], never overflows
    float r = (1.0f - t) / (1.0f + t);
    return copysignf(r, x);
}

__device__ __forceinline__ ushort f2bf(float f) {
    unsigned u = __float_as_uint(f);
    u += 0x7fffu + ((u >> 16) & 1u);
    return (ushort)(u >> 16);
}

__device__ __forceinline__ void gl_lds16(const ushort* g, ushort* l) {
    __builtin_amdgcn_global_load_lds(
        (const __attribute__((address_space(1))) void*)g,
        (__attribute__((address_space(3))) void*)l, 16, 0, 0);
}

// ================= ring-4 counted-vmcnt bf16 MFMA GEMM =================
// Tile 128x128, BK=32, 4 waves (2x2), each wave 64x64 = 4x4 frags of 16x16x32.
// LDS layout per 64-row half: [kgrp 4][row 64][8] -> conflict-free b128 reads
// (wave's 64 lanes cover all 32 banks exactly 2x). Staged linearly by
// global_load_lds with srow=tid&63, scol=(tid>>6)*8 (rule #21: both-sides-linear).
// Pipeline: 4-buffer ring, counted vmcnt (T4): own-wave vmcnt + s_barrier ==
// all waves' tile-t loads complete. Barrier count block-uniform.
template <class ALd, class WLd, class Epi>
__global__ __launch_bounds__(256) void gemm_ring(ALd al, WLd wl, Epi ep) {
    __shared__ ushort As[4 * 4096];
    __shared__ ushort Ws[4 * 4096];
    const int tid = threadIdx.x;
    const int lane = tid & 63;
    const int w = tid >> 6;
    const int wr = w >> 1, wc = w & 1;
    const int bn = blockIdx.x * 128 + al.bn0;
    const int bm = blockIdx.y * 128;
    const int srow = tid & 63;           // row within 64-row half
    const int scol = (tid >> 6) * 8;     // k-chunk (wave id picks kgrp)
    const int K = al.kdim(bn);
    const int nk = K >> 5;

    auto STAGE = [&](int kt, int buf) {
        const int k0 = kt * 32;
        ushort* ad = As + buf * 4096 + w * 512;
        ushort* wd = Ws + buf * 4096 + w * 512;
        gl_lds16(al.addr(bn, bm + srow, k0 + scol), ad);
        gl_lds16(al.addr(bn, bm + 64 + srow, k0 + scol), ad + 2048);
        gl_lds16(wl.addr(bm, bn + srow, k0 + scol), wd);
        gl_lds16(wl.addr(bm, bn + 64 + srow, k0 + scol), wd + 2048);
    };

    f32x4 acc[4][4];
#pragma unroll
    for (int m = 0; m < 4; ++m)
#pragma unroll
        for (int n = 0; n < 4; ++n) acc[m][n] = (f32x4)0.0f;

    STAGE(0, 0);
    if (nk > 1) STAGE(1, 1);
    if (nk > 2) STAGE(2, 2);

    const int foff = wr * 2048 + (lane >> 4) * 512 + (lane & 15) * 8;
    const int goff = wc * 2048 + (lane >> 4) * 512 + (lane & 15) * 8;

    for (int kt = 0; kt < nk; ++kt) {
        // own-wave counted wait, then join: after barrier, ALL waves' tile-kt
        // loads have landed (each waited its own before the barrier).
        if (kt + 2 < nk)      asm volatile("s_waitcnt vmcnt(8)" ::: "memory");
        else if (kt + 1 < nk) asm volatile("s_waitcnt vmcnt(4)" ::: "memory");
        else                  asm volatile("s_waitcnt vmcnt(0)" ::: "memory");
        __builtin_amdgcn_s_barrier();
        asm volatile("" ::: "memory");   // keep LDS reads below the barrier

        if (kt + 3 < nk) STAGE(kt + 3, (kt + 3) & 3);

        const ushort* asp = As + ((kt & 3) * 4096) + foff;
        const ushort* bsp = Ws + ((kt & 3) * 4096) + goff;
        bf16x8 af[4], bw[4];
#pragma unroll
        for (int m = 0; m < 4; ++m) af[m] = *(const bf16x8*)(asp + m * 128);
#pragma unroll
        for (int n = 0; n < 4; ++n) bw[n] = *(const bf16x8*)(bsp + n * 128);
#pragma unroll
        for (int m = 0; m < 4; ++m)
#pragma unroll
            for (int n = 0; n < 4; ++n)
                acc[m][n] = __builtin_amdgcn_mfma_f32_16x16x32_bf16(af[m], bw[n], acc[m][n], 0, 0, 0);
    }
    ep(bm, bn, wr, wc, lane, acc);
}

// ================= loaders =================
struct ALdEnc {  // rows: dir*1024+b ; cols: [x_t(128) | h(1024)]
    const ushort* xe; const ushort* h; int bn0;
    __device__ int kdim(int) const { return 1152; }
    __device__ const ushort* addr(int, int row, int k) const {
        return (k < 128) ? xe + (size_t)row * 128 + k
                         : h + (size_t)row * 1024 + (k - 128);
    }
};
struct WLdEnc {  // [2][4096][1152] gate-interleaved, dir = bm>>10
    const ushort* W;
    __device__ const ushort* addr(int bm, int n, int k) const {
        return W + ((size_t)(bm >> 10) * 4096 + n) * 1152 + k;
    }
};
struct ALdDec {  // rows: b ; cols: [x_t | h | z]; bn>=5120 -> hid1prev (K=1024)
    const ushort* xd; const ushort* h; const ushort* z;
    const ushort* hid1prev; int bn0;
    __device__ int kdim(int bn) const {
        return bn < 4096 ? 1152 : (bn < 5120 ? 1280 : 1024);
    }
    __device__ const ushort* addr(int bn, int row, int k) const {
        if (bn >= 5120) return hid1prev + (size_t)row * 1024 + k;
        if (k < 128) return xd + (size_t)row * 128 + k;
        if (k < 1152) return h + (size_t)row * 1024 + (k - 128);
        return z + (size_t)row * 128 + (k - 1152);
    }
};
struct WLdDec {  // [4096][1152] gates | [1024][1280] W1 | [128][1024] W2pad
    const ushort* Wg4; const ushort* W1; const ushort* W2p;
    __device__ const ushort* addr(int, int n, int k) const {
        if (n < 4096) return Wg4 + (size_t)n * 1152 + k;
        if (n < 5120) return W1 + (size_t)(n - 4096) * 1280 + k;
        return W2p + (size_t)(n - 5120) * 1024 + k;
    }
};
struct ALdHid {  // hidden = [h_f | h_b]
    const ushort* hF; int bn0;
    __device__ int kdim(int) const { return 2048; }
    __device__ const ushort* addr(int, int row, int k) const {
        return hF + ((size_t)((k >> 10) << 10) + row) * 1024 + (k & 1023);
    }
};
struct ALdPlain {
    const ushort* A; int ld; int K; int bn0;
    __device__ int kdim(int) const { return K; }
    __device__ const ushort* addr(int, int row, int k) const { return A + (size_t)row * ld + k; }
};
struct WLdPlain {
    const ushort* W; int ld;
    __device__ const ushort* addr(int, int n, int k) const { return W + (size_t)n * ld + k; }
};

// ================= epilogues =================
struct EpiEnc {  // fused encoder LSTM cell, gate-interleaved: frag n = gate n (i,f,g,o)
    const float* b_f; const float* b_b; const int* len; int t;
    float* c; const ushort* hc; ushort* hn;
    __device__ void operator()(int bm, int bn, int wr, int wc, int lane,
                               f32x4 (&acc)[4][4]) const {
        const int j = ((bn >> 6) + wc) * 16 + (lane & 15);
        const int rbase = bm + wr * 64 + ((lane >> 4) << 2);
#pragma unroll
        for (int m = 0; m < 4; ++m) {
#pragma unroll
            for (int r = 0; r < 4; ++r) {
                const int row = rbase + m * 16 + r;
                const int b = row & 1023;
                const float* bias = (row >> 10) ? b_b : b_f;
                const size_t o = (size_t)row * 1024 + j;
                if (t < len[b]) {
                    float gi = acc[m][0][r] + bias[j];
                    float gf = acc[m][1][r] + bias[1024 + j];
                    float gg = acc[m][2][r] + bias[2048 + j];
                    float go = acc[m][3][r] + bias[3072 + j];
                    float nc = sigf(gf) * c[o] + sigf(gi) * tanhfast(gg);
                    c[o] = nc;
                    hn[o] = f2bf(sigf(go) * tanhfast(nc));
                } else {
                    hn[o] = hc[o];
                }
            }
        }
    }
};

struct EpiDec {
    const float *bi, *bo, *bfv, *bg, *b1, *b2;
    float* c; ushort* hn; ushort* hid1cur;
    const int* tokens; const int* len; int t;
    float* accs;
    __device__ void operator()(int bm, int bn, int wr, int wc, int lane,
                               f32x4 (&acc)[4][4]) const {
        const int rbase = bm + wr * 64 + ((lane >> 4) << 2);
        if (bn < 4096) {            // fused decoder LSTM cell (i,o,f,g)
            const int j = ((bn >> 6) + wc) * 16 + (lane & 15);
#pragma unroll
            for (int m = 0; m < 4; ++m) {
#pragma unroll
                for (int r = 0; r < 4; ++r) {
                    const int b = rbase + m * 16 + r;
                    const size_t o = (size_t)b * 1024 + j;
                    float gi = sigf(acc[m][0][r] + bi[j]);
                    float go = sigf(acc[m][1][r] + bo[j]);
                    float gf = sigf(acc[m][2][r] + bfv[j]);
                    float gg = tanhfast(acc[m][3][r] + bg[j]);
                    float nc = gf * c[o] + gi * gg;
                    c[o] = nc;
                    hn[o] = f2bf(go * tanhfast(nc));
                }
            }
        } else if (bn < 5120) {     // hid1 = relu(ah@W1^T + b1), bf16
            const int cb = (bn - 4096) + wc * 64;
#pragma unroll
            for (int m = 0; m < 4; ++m)
#pragma unroll
                for (int n = 0; n < 4; ++n) {
                    const int col = cb + n * 16 + (lane & 15);
#pragma unroll
                    for (int r = 0; r < 4; ++r)
                        hid1cur[(size_t)(rbase + m * 16 + r) * 1024 + col] =
                            f2bf(fmaxf(acc[m][n][r] + b1[col], 0.0f));
                }
        } else {                    // scores(t-1): CE/argmax, wave-parallel
            if (wc != 0) return;
            const int ts = t - 1;
            const int col0 = lane & 15;
            const bool v1ok = col0 < (V_ - 16);   // cols 16..20
            const float b2v0 = b2[col0];
            const float b2v1 = v1ok ? b2[16 + col0] : 0.0f;
            float ce_loc = 0.f, cor_loc = 0.f, msk_loc = 0.f;
#pragma unroll
            for (int m = 0; m < 4; ++m) {
#pragma unroll
                for (int r = 0; r < 4; ++r) {
                    const int b = rbase + m * 16 + r;
                    const int lb = len[b];
                    float v0 = acc[m][0][r] + b2v0;
                    float v1 = v1ok ? (acc[m][1][r] + b2v1) : -1e30f;
                    float mv; int mi;
                    if (v1 > v0) { mv = v1; mi = 16 + col0; } else { mv = v0; mi = col0; }
#pragma unroll
                    for (int s = 1; s < 16; s <<= 1) {
                        float ov = __shfl_xor(mv, s);
                        int oi = __shfl_xor(mi, s);
                        if (ov > mv || (ov == mv && oi < mi)) { mv = ov; mi = oi; }
                    }
                    float se = expf(v0 - mv) + (v1ok ? expf(v1 - mv) : 0.0f);
#pragma unroll
                    for (int s = 1; s < 16; s <<= 1) se += __shfl_xor(se, s);
                    float lse = mv + logf(se);
                    int tgt = (ts < lb) ? tokens[b * T_ + ts] : 0;
                    int srcl = (lane & 48) | (tgt & 15);
                    float sv0 = __shfl(v0, srcl);
                    float sv1 = __shfl(v1, srcl);
                    float stgt = (tgt < 16) ? sv0 : sv1;
                    if (ts <= lb && col0 == 0) {
                        ce_loc += lse - stgt;
                        cor_loc += (mi == tgt) ? 1.0f : 0.0f;
                        msk_loc += 1.0f;
                    }
                }
            }
            float ce = __shfl(ce_loc, 0) + __shfl(ce_loc, 16) + __shfl(ce_loc, 32) + __shfl(ce_loc, 48);
            float co = __shfl(cor_loc, 0) + __shfl(cor_loc, 16) + __shfl(cor_loc, 32) + __shfl(cor_loc, 48);
            float mk = __shfl(msk_loc, 0) + __shfl(msk_loc, 16) + __shfl(msk_loc, 32) + __shfl(msk_loc, 48);
            if (lane == 0) {
                atomicAdd(&accs[0], ce);
                atomicAdd(&accs[1], co);
                atomicAdd(&accs[2], mk);
            }
        }
    }
};

struct EpiStoreF32 {
    float* out; int ldc;
    __device__ void operator()(int bm, int bn, int wr, int wc, int lane,
                               f32x4 (&acc)[4][4]) const {
        const int rbase = bm + wr * 64 + ((lane >> 4) << 2);
        const int cbase = bn + wc * 64 + (lane & 15);
#pragma unroll
        for (int m = 0; m < 4; ++m)
#pragma unroll
            for (int n = 0; n < 4; ++n)
#pragma unroll
                for (int r = 0; r < 4; ++r)
                    out[(size_t)(rbase + m * 16 + r) * ldc + cbase + n * 16] = acc[m][n][r];
    }
};
struct EpiBiasBf16 {
    ushort* out; const float* bias;
    __device__ void operator()(int bm, int bn, int wr, int wc, int lane,
                               f32x4 (&acc)[4][4]) const {
        const int rbase = bm + wr * 64 + ((lane >> 4) << 2);
        const int cbase = bn + wc * 64 + (lane & 15);
#pragma unroll
        for (int m = 0; m < 4; ++m)
#pragma unroll
            for (int n = 0; n < 4; ++n) {
                const int col = cbase + n * 16;
#pragma unroll
                for (int r = 0; r < 4; ++r)
                    out[(size_t)(rbase + m * 16 + r) * 1024 + col] = f2bf(acc[m][n][r] + bias[col]);
            }
    }
};

// ================= packing / elementwise =================
__global__ void pack_cols(const float* __restrict__ src, int src_ld,
                          ushort* __restrict__ dst, int dst_ld, int dcol0,
                          int rows, int cols) {
    int i = blockIdx.x * 256 + threadIdx.x;
    int c4cnt = cols >> 2;
    if (i >= rows * c4cnt) return;
    int r = i / c4cnt, c4 = (i - r * c4cnt) * 4;
    float4 v = *(const float4*)(src + (size_t)r * src_ld + c4);
    ushort4 o = { f2bf(v.x), f2bf(v.y), f2bf(v.z), f2bf(v.w) };
    *(ushort4*)(dst + (size_t)r * dst_ld + dcol0 + c4) = o;
}

__global__ void pack_gates_enc(const float* __restrict__ Wih_f, const float* __restrict__ Whh_f,
                               const float* __restrict__ Wih_b, const float* __restrict__ Whh_b,
                               ushort* __restrict__ dst) {
    int i = blockIdx.x * 256 + threadIdx.x;   // 2*4096*288
    if (i >= 2 * 4096 * 288) return;
    int c4 = (i % 288) * 4;
    int p = (i / 288) & 4095;
    int dir = i / (288 * 4096);
    int j = ((p >> 6) << 4) + (p & 15);
    int g = (p >> 4) & 3;
    int srow = g * 1024 + j;
    float4 v;
    if (c4 < 128) {
        const float* s = dir ? Wih_b : Wih_f;
        v = *(const float4*)(s + (size_t)srow * 128 + c4);
    } else {
        const float* s = dir ? Whh_b : Whh_f;
        v = *(const float4*)(s + (size_t)srow * 1024 + (c4 - 128));
    }
    ushort4 o = { f2bf(v.x), f2bf(v.y), f2bf(v.z), f2bf(v.w) };
    *(ushort4*)(dst + ((size_t)dir * 4096 + p) * 1152 + c4) = o;
}

__global__ void pack_gates_dec(const float* __restrict__ Wi, const float* __restrict__ Wo,
                               const float* __restrict__ Wf, const float* __restrict__ Wg,
                               ushort* __restrict__ dst) {
    int i = blockIdx.x * 256 + threadIdx.x;   // 4096*288
    if (i >= 4096 * 288) return;
    int c4 = (i % 288) * 4;
    int p = i / 288;
    int j = ((p >> 6) << 4) + (p & 15);
    int g = (p >> 4) & 3;
    const float* s = (g == 0) ? Wi : (g == 1) ? Wo : (g == 2) ? Wf : Wg;
    float4 v = *(const float4*)(s + (size_t)j * 1152 + c4);
    ushort4 o = { f2bf(v.x), f2bf(v.y), f2bf(v.z), f2bf(v.w) };
    *(ushort4*)(dst + (size_t)p * 1152 + c4) = o;
}

__global__ void pack_w2(const float* __restrict__ W2, ushort* __restrict__ dst) {
    int i = blockIdx.x * 256 + threadIdx.x;   // 128*256
    if (i >= 128 * 256) return;
    int r = i >> 8, c4 = (i & 255) * 4;
    ushort4 o = { 0, 0, 0, 0 };
    if (r < V_) {
        float4 v = *(const float4*)(W2 + (size_t)r * 1024 + c4);
        o = ushort4{ f2bf(v.x), f2bf(v.y), f2bf(v.z), f2bf(v.w) };
    }
    *(ushort4*)(dst + (size_t)r * 1024 + c4) = o;
}

__global__ void pack_xenc(const float* __restrict__ xenc, const int* __restrict__ len,
                          ushort* __restrict__ xe) {
    int i = blockIdx.x * 256 + threadIdx.x;   // 15*2048*32
    if (i >= 15 * 2048 * 32) return;
    int c4 = (i & 31) * 4;
    int r = (i >> 5) & 2047;
    int t = i >> 16;
    int dir = r >> 10, b = r & 1023;
    int tt = t;
    if (dir) {
        int ri = len[b] - 1 - t;
        tt = ri < 0 ? 0 : (ri > T_ - 1 ? T_ - 1 : ri);
    }
    float4 v = *(const float4*)(xenc + ((size_t)b * T_ + tt) * 128 + c4);
    ushort4 o = { f2bf(v.x), f2bf(v.y), f2bf(v.z), f2bf(v.w) };
    *(ushort4*)(xe + ((size_t)t * 2048 + r) * 128 + c4) = o;
}

__global__ void pack_xdec(const float* __restrict__ emb, const int* __restrict__ tokens,
                          ushort* __restrict__ xd) {
    int i = blockIdx.x * 256 + threadIdx.x;   // 15*1024*32
    if (i >= 15 * 1024 * 32) return;
    int c4 = (i & 31) * 4;
    int b = (i >> 5) & 1023;
    int t = i >> 15;
    ushort4 o = { 0, 0, 0, 0 };
    if (t > 0) {
        int tok = tokens[(size_t)b * T_ + (t - 1)];
        float4 v = *(const float4*)(emb + (size_t)tok * 128 + c4);
        o = ushort4{ f2bf(v.x), f2bf(v.y), f2bf(v.z), f2bf(v.w) };
    }
    *(ushort4*)(xd + ((size_t)t * 1024 + b) * 128 + c4) = o;
}

__global__ void init_zero(float* cenc, float* cdec, ushort* hA, float* accs) {
    int i = blockIdx.x * 256 + threadIdx.x;
    if (i < 2 * 1024 * 1024) { cenc[i] = 0.0f; hA[i] = 0; }
    if (i < 1024 * 1024) cdec[i] = 0.0f;
    if (i < 8) accs[i] = 0.0f;
}

__global__ void latent_ew(const float* __restrict__ ml, const float* __restrict__ bmv,
                          const float* __restrict__ blv, const float* __restrict__ eps,
                          ushort* __restrict__ zp, float* __restrict__ klacc) {
    int idx = blockIdx.x * 256 + threadIdx.x;
    int b = idx >> 7, l = idx & (L_ - 1);
    float mean = ml[(size_t)b * 256 + l] + bmv[l];
    float logv = ml[(size_t)b * 256 + L_ + l] + blv[l];
    zp[idx] = f2bf(eps[idx] * expf(0.5f * logv) + mean);
    float part = 1.0f + logv - mean * mean - expf(logv);
    for (int off = 32; off; off >>= 1) part += __shfl_down(part, off);
    __shared__ float s[4];
    int lane = threadIdx.x & 63, wv = threadIdx.x >> 6;
    if (lane == 0) s[wv] = part;
    __syncthreads();
    if (threadIdx.x == 0) atomicAdd(klacc, s[0] + s[1] + s[2] + s[3]);
}

__global__ void finalize_k(const float* accs, float* out) {
    if (threadIdx.x == 0 && blockIdx.x == 0) {
        float kl = -0.5f * accs[3] / (float)B_;
        float amino = accs[0] / (float)B_;
        out[0] = amino + 0.1f * kl;
        out[1] = amino;
        out[2] = kl;
        out[3] = accs[1] / accs[2];
    }
}

// ================= host =================
extern "C" void kernel_launch(void* const* d_in, const int* in_sizes, int n_in,
                              void* d_out, int out_size, void* d_ws, size_t ws_size,
                              hipStream_t stream) {
    (void)in_sizes; (void)n_in; (void)out_size; (void)ws_size;
    const float* x_enc  = (const float*)d_in[0];
    const int*   tokens = (const int*)d_in[1];
    const int*   lengths= (const int*)d_in[2];
    const float* eps    = (const float*)d_in[3];
    const float* emb    = (const float*)d_in[4];
    const float* Wih_f  = (const float*)d_in[5];
    const float* Whh_f  = (const float*)d_in[6];
    const float* b_f    = (const float*)d_in[7];
    const float* Wih_b  = (const float*)d_in[8];
    const float* Whh_b  = (const float*)d_in[9];
    const float* b_b    = (const float*)d_in[10];
    const float* Wm     = (const float*)d_in[11];
    const float* bm     = (const float*)d_in[12];
    const float* Wl     = (const float*)d_in[13];
    const float* bl     = (const float*)d_in[14];
    const float* Wz     = (const float*)d_in[15];
    const float* bz     = (const float*)d_in[16];
    const float* Wi     = (const float*)d_in[17];
    const float* bi     = (const float*)d_in[18];
    const float* Wo     = (const float*)d_in[19];
    const float* bo     = (const float*)d_in[20];
    const float* Wfm    = (const float*)d_in[21];
    const float* bf     = (const float*)d_in[22];
    const float* Wg     = (const float*)d_in[23];
    const float* bg     = (const float*)d_in[24];
    const float* W1     = (const float*)d_in[25];
    const float* b1     = (const float*)d_in[26];
    const float* W2     = (const float*)d_in[27];
    const float* b2     = (const float*)d_in[28];

    float*  cenc = (float*)d_ws;                    // 2M f32
    float*  cdec = cenc + 2 * 1024 * 1024;          // 1M f32
    float*  ml   = cdec + 1024 * 1024;              // 256K f32
    float*  accs = ml + 1024 * 256;                 // 8 (+pad 64)
    ushort* hA   = (ushort*)(accs + 64);            // 2M
    ushort* hB   = hA + 2 * 1024 * 1024;
    ushort* hdA  = hB + 2 * 1024 * 1024;            // 1M
    ushort* hdB  = hdA + 1024 * 1024;
    ushort* h1A  = hdB + 1024 * 1024;               // 1M
    ushort* h1B  = h1A + 1024 * 1024;
    ushort* zp   = h1B + 1024 * 1024;               // 128K
    ushort* xe   = zp + 1024 * 128;                 // 15*2048*128
    ushort* xd   = xe + 15 * 2048 * 128;            // 15*1024*128
    ushort* Wenc = xd + 15 * 1024 * 128;            // 2*4096*1152
    ushort* Wdec = Wenc + 2 * 4096 * 1152;          // 4096*1152
    ushort* W1p  = Wdec + 4096 * 1152;              // 1024*1280
    ushort* Wml  = W1p + 1024 * 1280;               // 256*2048
    ushort* Wzp  = Wml + 256 * 2048;                // 1024*128
    ushort* W2p  = Wzp + 1024 * 128;                // 128*1024

    init_zero<<<8192, 256, 0, stream>>>(cenc, cdec, hA, accs);
    pack_gates_enc<<<9216, 256, 0, stream>>>(Wih_f, Whh_f, Wih_b, Whh_b, Wenc);
    pack_gates_dec<<<4608, 256, 0, stream>>>(Wi, Wo, Wfm, Wg, Wdec);
    pack_cols<<<1280, 256, 0, stream>>>(W1, 1280, W1p, 1280, 0, 1024, 1280);
    pack_cols<<<256, 256, 0, stream>>>(Wm, 2048, Wml, 2048, 0, L_, 2048);
    pack_cols<<<256, 256, 0, stream>>>(Wl, 2048, Wml + L_ * 2048, 2048, 0, L_, 2048);
    pack_cols<<<128, 256, 0, stream>>>(Wz, L_, Wzp, L_, 0, H_, L_);
    pack_w2<<<128, 256, 0, stream>>>(W2, W2p);
    pack_xenc<<<3840, 256, 0, stream>>>(x_enc, lengths, xe);
    pack_xdec<<<1920, 256, 0, stream>>>(emb, tokens, xd);

    // ---- encoder ----
    {
        const ushort* hc = hA; ushort* hn = hB;
        for (int t = 0; t < T_; ++t) {
            gemm_ring<<<dim3(32, 16), 256, 0, stream>>>(
                ALdEnc{ xe + (size_t)t * 2048 * 128, hc, 0 }, WLdEnc{ Wenc },
                EpiEnc{ b_f, b_b, lengths, t, cenc, hc, hn });
            const ushort* tmp = hn; hn = (ushort*)hc; hc = tmp;
        }
        gemm_ring<<<dim3(2, 8), 256, 0, stream>>>(
            ALdHid{ hc, 0 }, WLdPlain{ Wml, 2048 }, EpiStoreF32{ ml, 256 });
    }
    latent_ew<<<512, 256, 0, stream>>>(ml, bm, bl, eps, zp, &accs[3]);
    gemm_ring<<<dim3(8, 8), 256, 0, stream>>>(
        ALdPlain{ zp, 128, 128, 0 }, WLdPlain{ Wzp, 128 }, EpiBiasBf16{ hdA, bz });

    // ---- decoder: scores(t-1) fused as extra bn segment ----
    {
        const ushort* dc = hdA; ushort* dn = hdB;
        for (int t = 0; t < T_; ++t) {
            ushort* h1c = (t & 1) ? h1B : h1A;
            const ushort* h1p = (t & 1) ? h1A : h1B;
            dim3 grid(t == 0 ? 40 : 41, 8);
            gemm_ring<<<grid, 256, 0, stream>>>(
                ALdDec{ xd + (size_t)t * 1024 * 128, dc, zp, h1p, 0 },
                WLdDec{ Wdec, W1p, W2p },
                EpiDec{ bi, bo, bf, bg, b1, b2, cdec, dn, h1c, tokens, lengths, t, accs });
            const ushort* tmp = dn; dn = (ushort*)dc; dc = tmp;
        }
        const ushort* h1p14 = ((T_ - 1) & 1) ? h1B : h1A;  // hid1 written at t=14
        gemm_ring<<<dim3(1, 8), 256, 0, stream>>>(
            ALdDec{ xd, dc, zp, h1p14, 5120 },
            WLdDec{ Wdec, W1p, W2p },
            EpiDec{ bi, bo, bf, bg, b1, b2, cdec, hdB, h1B, tokens, lengths, T_, accs });
    }

    finalize_k<<<1, 64, 0, stream>>>(accs, (float*)d_out);
}

// Round 6
// 1724.886 us; speedup vs baseline: 1.2903x; 1.2903x over previous
//
#include <hip/hip_runtime.h>
#include <math.h>

#define B_ 1024
#define T_ 15
#define E_ 128
#define H_ 1024
#define L_ 128
#define V_ 21

typedef __attribute__((ext_vector_type(8))) short bf16x8;
typedef __attribute__((ext_vector_type(4))) float f32x4;

// overflow-safe fast sigmoid / tanh (v_exp_f32 path)
__device__ __forceinline__ float sigf(float x) { return 1.0f / (1.0f + __expf(-x)); }
__device__ __forceinline__ float tanhfast(float x) {
    float t = __expf(-2.0f * fabsf(x));          // in (0,1], never overflows
    float r = (1.0f - t) / (1.0f + t);
    return copysignf(r, x);
}

__device__ __forceinline__ ushort f2bf(float f) {
    unsigned u = __float_as_uint(f);
    u += 0x7fffu + ((u >> 16) & 1u);
    return (ushort)(u >> 16);
}

__device__ __forceinline__ void gl_lds16(const ushort* g, ushort* l) {
    __builtin_amdgcn_global_load_lds(
        (const __attribute__((address_space(1))) void*)g,
        (__attribute__((address_space(3))) void*)l, 16, 0, 0);
}

// ================= ring-3 counted-vmcnt bf16 MFMA GEMM =================
// Tile 128x128, BK=32, 4 waves (2x2), each wave 64x64 = 4x4 frags of 16x16x32.
// Staging geometry = R4's coalesced map: wave w writes 16 rows x 64B contiguous
// (srow=tid>>2, scol=(tid&3)*8, linear LDS dest). Fragment reads keep R4 layout
// (8-way bank conflict accepted: measured ~8% of time, vs coalescing 2x fetch).
// Pipeline: 3-buffer ring, counted vmcnt: own-wave vmcnt(4) + s_barrier ==
// tile-kt loads complete block-wide, tile kt+1 stays in flight across barrier.
template <class ALd, class WLd, class Epi>
__global__ __launch_bounds__(256) void gemm_ring(ALd al, WLd wl, Epi ep) {
    __shared__ ushort As[3 * 4096];
    __shared__ ushort Ws[3 * 4096];
    const int tid = threadIdx.x;
    const int lane = tid & 63;
    const int w = tid >> 6;
    const int wr = w >> 1, wc = w & 1;
    const int bn = blockIdx.x * 128 + al.bn0;
    const int bm = blockIdx.y * 128;
    const int srow = tid >> 2;           // 0..63 (wave w covers rows w*16..w*16+15)
    const int scol = (tid & 3) * 8;      // 0,8,16,24
    const int K = al.kdim(bn);
    const int nk = K >> 5;

    auto STAGE = [&](int kt, int buf) {
        const int k0 = kt * 32;
        ushort* ad = As + buf * 4096 + w * 512;
        ushort* wd = Ws + buf * 4096 + w * 512;
        gl_lds16(al.addr(bn, bm + srow, k0 + scol), ad);
        gl_lds16(al.addr(bn, bm + 64 + srow, k0 + scol), ad + 2048);
        gl_lds16(wl.addr(bm, bn + srow, k0 + scol), wd);
        gl_lds16(wl.addr(bm, bn + 64 + srow, k0 + scol), wd + 2048);
    };

    f32x4 acc[4][4];
#pragma unroll
    for (int m = 0; m < 4; ++m)
#pragma unroll
        for (int n = 0; n < 4; ++n) acc[m][n] = (f32x4)0.0f;

    STAGE(0, 0);
    if (nk > 1) STAGE(1, 1);

    const int frow = lane & 15, fk = (lane >> 4) * 8;
    const int foff = (wr * 64 + frow) * 32 + fk;
    const int goff = (wc * 64 + frow) * 32 + fk;

    int cbuf = 0, sbuf = 2;
    for (int kt = 0; kt < nk; ++kt) {
        // own-wave counted wait + join: after barrier, ALL waves' tile-kt loads
        // have landed (each waited its own 4 before the barrier).
        if (kt + 1 < nk) asm volatile("s_waitcnt vmcnt(4)" ::: "memory");
        else             asm volatile("s_waitcnt vmcnt(0)" ::: "memory");
        __builtin_amdgcn_s_barrier();
        asm volatile("" ::: "memory");   // keep LDS reads below the barrier

        if (kt + 2 < nk) STAGE(kt + 2, sbuf);

        const ushort* asp = As + cbuf * 4096 + foff;
        const ushort* bsp = Ws + cbuf * 4096 + goff;
        bf16x8 af[4], bw[4];
#pragma unroll
        for (int m = 0; m < 4; ++m) af[m] = *(const bf16x8*)(asp + m * 512);
#pragma unroll
        for (int n = 0; n < 4; ++n) bw[n] = *(const bf16x8*)(bsp + n * 512);
#pragma unroll
        for (int m = 0; m < 4; ++m)
#pragma unroll
            for (int n = 0; n < 4; ++n)
                acc[m][n] = __builtin_amdgcn_mfma_f32_16x16x32_bf16(af[m], bw[n], acc[m][n], 0, 0, 0);

        cbuf = (cbuf == 2) ? 0 : cbuf + 1;
        sbuf = (sbuf == 2) ? 0 : sbuf + 1;
    }
    ep(bm, bn, wr, wc, lane, acc);
}

// ================= loaders =================
struct ALdEnc {  // rows: dir*1024+b ; cols: [x_t(128) | h(1024)]
    const ushort* xe; const ushort* h; int bn0;
    __device__ int kdim(int) const { return 1152; }
    __device__ const ushort* addr(int, int row, int k) const {
        return (k < 128) ? xe + (size_t)row * 128 + k
                         : h + (size_t)row * 1024 + (k - 128);
    }
};
struct WLdEnc {  // [2][4096][1152] gate-interleaved, dir = bm>>10
    const ushort* W;
    __device__ const ushort* addr(int bm, int n, int k) const {
        return W + ((size_t)(bm >> 10) * 4096 + n) * 1152 + k;
    }
};
struct ALdDec {  // rows: b ; cols: [x_t | h | z]; bn>=5120 -> hid1prev (K=1024)
    const ushort* xd; const ushort* h; const ushort* z;
    const ushort* hid1prev; int bn0;
    __device__ int kdim(int bn) const {
        return bn < 4096 ? 1152 : (bn < 5120 ? 1280 : 1024);
    }
    __device__ const ushort* addr(int bn, int row, int k) const {
        if (bn >= 5120) return hid1prev + (size_t)row * 1024 + k;
        if (k < 128) return xd + (size_t)row * 128 + k;
        if (k < 1152) return h + (size_t)row * 1024 + (k - 128);
        return z + (size_t)row * 128 + (k - 1152);
    }
};
struct WLdDec {  // [4096][1152] gates | [1024][1280] W1 | [128][1024] W2pad
    const ushort* Wg4; const ushort* W1; const ushort* W2p;
    __device__ const ushort* addr(int, int n, int k) const {
        if (n < 4096) return Wg4 + (size_t)n * 1152 + k;
        if (n < 5120) return W1 + (size_t)(n - 4096) * 1280 + k;
        return W2p + (size_t)(n - 5120) * 1024 + k;
    }
};
struct ALdHid {  // hidden = [h_f | h_b]
    const ushort* hF; int bn0;
    __device__ int kdim(int) const { return 2048; }
    __device__ const ushort* addr(int, int row, int k) const {
        return hF + ((size_t)((k >> 10) << 10) + row) * 1024 + (k & 1023);
    }
};
struct ALdPlain {
    const ushort* A; int ld; int K; int bn0;
    __device__ int kdim(int) const { return K; }
    __device__ const ushort* addr(int, int row, int k) const { return A + (size_t)row * ld + k; }
};
struct WLdPlain {
    const ushort* W; int ld;
    __device__ const ushort* addr(int, int n, int k) const { return W + (size_t)n * ld + k; }
};

// ================= epilogues =================
struct EpiEnc {  // fused encoder LSTM cell, gate-interleaved: frag n = gate n (i,f,g,o)
    const float* b_f; const float* b_b; const int* len; int t;
    float* c; const ushort* hc; ushort* hn;
    __device__ void operator()(int bm, int bn, int wr, int wc, int lane,
                               f32x4 (&acc)[4][4]) const {
        const int j = ((bn >> 6) + wc) * 16 + (lane & 15);
        const int rbase = bm + wr * 64 + ((lane >> 4) << 2);
#pragma unroll
        for (int m = 0; m < 4; ++m) {
#pragma unroll
            for (int r = 0; r < 4; ++r) {
                const int row = rbase + m * 16 + r;
                const int b = row & 1023;
                const float* bias = (row >> 10) ? b_b : b_f;
                const size_t o = (size_t)row * 1024 + j;
                if (t < len[b]) {
                    float gi = acc[m][0][r] + bias[j];
                    float gf = acc[m][1][r] + bias[1024 + j];
                    float gg = acc[m][2][r] + bias[2048 + j];
                    float go = acc[m][3][r] + bias[3072 + j];
                    float nc = sigf(gf) * c[o] + sigf(gi) * tanhfast(gg);
                    c[o] = nc;
                    hn[o] = f2bf(sigf(go) * tanhfast(nc));
                } else {
                    hn[o] = hc[o];
                }
            }
        }
    }
};

struct EpiDec {
    const float *bi, *bo, *bfv, *bg, *b1, *b2;
    float* c; ushort* hn; ushort* hid1cur;
    const int* tokens; const int* len; int t;
    float* accs;
    __device__ void operator()(int bm, int bn, int wr, int wc, int lane,
                               f32x4 (&acc)[4][4]) const {
        const int rbase = bm + wr * 64 + ((lane >> 4) << 2);
        if (bn < 4096) {            // fused decoder LSTM cell (i,o,f,g)
            const int j = ((bn >> 6) + wc) * 16 + (lane & 15);
#pragma unroll
            for (int m = 0; m < 4; ++m) {
#pragma unroll
                for (int r = 0; r < 4; ++r) {
                    const int b = rbase + m * 16 + r;
                    const size_t o = (size_t)b * 1024 + j;
                    float gi = sigf(acc[m][0][r] + bi[j]);
                    float go = sigf(acc[m][1][r] + bo[j]);
                    float gf = sigf(acc[m][2][r] + bfv[j]);
                    float gg = tanhfast(acc[m][3][r] + bg[j]);
                    float nc = gf * c[o] + gi * gg;
                    c[o] = nc;
                    hn[o] = f2bf(go * tanhfast(nc));
                }
            }
        } else if (bn < 5120) {     // hid1 = relu(ah@W1^T + b1), bf16
            const int cb = (bn - 4096) + wc * 64;
#pragma unroll
            for (int m = 0; m < 4; ++m)
#pragma unroll
                for (int n = 0; n < 4; ++n) {
                    const int col = cb + n * 16 + (lane & 15);
#pragma unroll
                    for (int r = 0; r < 4; ++r)
                        hid1cur[(size_t)(rbase + m * 16 + r) * 1024 + col] =
                            f2bf(fmaxf(acc[m][n][r] + b1[col], 0.0f));
                }
        } else {                    // scores(t-1): CE/argmax, wave-parallel
            if (wc != 0) return;
            const int ts = t - 1;
            const int col0 = lane & 15;
            const bool v1ok = col0 < (V_ - 16);   // cols 16..20
            const float b2v0 = b2[col0];
            const float b2v1 = v1ok ? b2[16 + col0] : 0.0f;
            float ce_loc = 0.f, cor_loc = 0.f, msk_loc = 0.f;
#pragma unroll
            for (int m = 0; m < 4; ++m) {
#pragma unroll
                for (int r = 0; r < 4; ++r) {
                    const int b = rbase + m * 16 + r;
                    const int lb = len[b];
                    float v0 = acc[m][0][r] + b2v0;
                    float v1 = v1ok ? (acc[m][1][r] + b2v1) : -1e30f;
                    float mv; int mi;
                    if (v1 > v0) { mv = v1; mi = 16 + col0; } else { mv = v0; mi = col0; }
#pragma unroll
                    for (int s = 1; s < 16; s <<= 1) {
                        float ov = __shfl_xor(mv, s);
                        int oi = __shfl_xor(mi, s);
                        if (ov > mv || (ov == mv && oi < mi)) { mv = ov; mi = oi; }
                    }
                    float se = expf(v0 - mv) + (v1ok ? expf(v1 - mv) : 0.0f);
#pragma unroll
                    for (int s = 1; s < 16; s <<= 1) se += __shfl_xor(se, s);
                    float lse = mv + logf(se);
                    int tgt = (ts < lb) ? tokens[b * T_ + ts] : 0;
                    int srcl = (lane & 48) | (tgt & 15);
                    float sv0 = __shfl(v0, srcl);
                    float sv1 = __shfl(v1, srcl);
                    float stgt = (tgt < 16) ? sv0 : sv1;
                    if (ts <= lb && col0 == 0) {
                        ce_loc += lse - stgt;
                        cor_loc += (mi == tgt) ? 1.0f : 0.0f;
                        msk_loc += 1.0f;
                    }
                }
            }
            float ce = __shfl(ce_loc, 0) + __shfl(ce_loc, 16) + __shfl(ce_loc, 32) + __shfl(ce_loc, 48);
            float co = __shfl(cor_loc, 0) + __shfl(cor_loc, 16) + __shfl(cor_loc, 32) + __shfl(cor_loc, 48);
            float mk = __shfl(msk_loc, 0) + __shfl(msk_loc, 16) + __shfl(msk_loc, 32) + __shfl(msk_loc, 48);
            if (lane == 0) {
                atomicAdd(&accs[0], ce);
                atomicAdd(&accs[1], co);
                atomicAdd(&accs[2], mk);
            }
        }
    }
};

struct EpiStoreF32 {
    float* out; int ldc;
    __device__ void operator()(int bm, int bn, int wr, int wc, int lane,
                               f32x4 (&acc)[4][4]) const {
        const int rbase = bm + wr * 64 + ((lane >> 4) << 2);
        const int cbase = bn + wc * 64 + (lane & 15);
#pragma unroll
        for (int m = 0; m < 4; ++m)
#pragma unroll
            for (int n = 0; n < 4; ++n)
#pragma unroll
                for (int r = 0; r < 4; ++r)
                    out[(size_t)(rbase + m * 16 + r) * ldc + cbase + n * 16] = acc[m][n][r];
    }
};
struct EpiBiasBf16 {
    ushort* out; const float* bias;
    __device__ void operator()(int bm, int bn, int wr, int wc, int lane,
                               f32x4 (&acc)[4][4]) const {
        const int rbase = bm + wr * 64 + ((lane >> 4) << 2);
        const int cbase = bn + wc * 64 + (lane & 15);
#pragma unroll
        for (int m = 0; m < 4; ++m)
#pragma unroll
            for (int n = 0; n < 4; ++n) {
                const int col = cbase + n * 16;
#pragma unroll
                for (int r = 0; r < 4; ++r)
                    out[(size_t)(rbase + m * 16 + r) * 1024 + col] = f2bf(acc[m][n][r] + bias[col]);
            }
    }
};

// ================= packing / elementwise =================
__global__ void pack_cols(const float* __restrict__ src, int src_ld,
                          ushort* __restrict__ dst, int dst_ld, int dcol0,
                          int rows, int cols) {
    int i = blockIdx.x * 256 + threadIdx.x;
    int c4cnt = cols >> 2;
    if (i >= rows * c4cnt) return;
    int r = i / c4cnt, c4 = (i - r * c4cnt) * 4;
    float4 v = *(const float4*)(src + (size_t)r * src_ld + c4);
    ushort4 o = { f2bf(v.x), f2bf(v.y), f2bf(v.z), f2bf(v.w) };
    *(ushort4*)(dst + (size_t)r * dst_ld + dcol0 + c4) = o;
}

__global__ void pack_gates_enc(const float* __restrict__ Wih_f, const float* __restrict__ Whh_f,
                               const float* __restrict__ Wih_b, const float* __restrict__ Whh_b,
                               ushort* __restrict__ dst) {
    int i = blockIdx.x * 256 + threadIdx.x;   // 2*4096*288
    if (i >= 2 * 4096 * 288) return;
    int c4 = (i % 288) * 4;
    int p = (i / 288) & 4095;
    int dir = i / (288 * 4096);
    int j = ((p >> 6) << 4) + (p & 15);
    int g = (p >> 4) & 3;
    int srow = g * 1024 + j;
    float4 v;
    if (c4 < 128) {
        const float* s = dir ? Wih_b : Wih_f;
        v = *(const float4*)(s + (size_t)srow * 128 + c4);
    } else {
        const float* s = dir ? Whh_b : Whh_f;
        v = *(const float4*)(s + (size_t)srow * 1024 + (c4 - 128));
    }
    ushort4 o = { f2bf(v.x), f2bf(v.y), f2bf(v.z), f2bf(v.w) };
    *(ushort4*)(dst + ((size_t)dir * 4096 + p) * 1152 + c4) = o;
}

__global__ void pack_gates_dec(const float* __restrict__ Wi, const float* __restrict__ Wo,
                               const float* __restrict__ Wf, const float* __restrict__ Wg,
                               ushort* __restrict__ dst) {
    int i = blockIdx.x * 256 + threadIdx.x;   // 4096*288
    if (i >= 4096 * 288) return;
    int c4 = (i % 288) * 4;
    int p = i / 288;
    int j = ((p >> 6) << 4) + (p & 15);
    int g = (p >> 4) & 3;
    const float* s = (g == 0) ? Wi : (g == 1) ? Wo : (g == 2) ? Wf : Wg;
    float4 v = *(const float4*)(s + (size_t)j * 1152 + c4);
    ushort4 o = { f2bf(v.x), f2bf(v.y), f2bf(v.z), f2bf(v.w) };
    *(ushort4*)(dst + (size_t)p * 1152 + c4) = o;
}

__global__ void pack_w2(const float* __restrict__ W2, ushort* __restrict__ dst) {
    int i = blockIdx.x * 256 + threadIdx.x;   // 128*256
    if (i >= 128 * 256) return;
    int r = i >> 8, c4 = (i & 255) * 4;
    ushort4 o = { 0, 0, 0, 0 };
    if (r < V_) {
        float4 v = *(const float4*)(W2 + (size_t)r * 1024 + c4);
        o = ushort4{ f2bf(v.x), f2bf(v.y), f2bf(v.z), f2bf(v.w) };
    }
    *(ushort4*)(dst + (size_t)r * 1024 + c4) = o;
}

__global__ void pack_xenc(const float* __restrict__ xenc, const int* __restrict__ len,
                          ushort* __restrict__ xe) {
    int i = blockIdx.x * 256 + threadIdx.x;   // 15*2048*32
    if (i >= 15 * 2048 * 32) return;
    int c4 = (i & 31) * 4;
    int r = (i >> 5) & 2047;
    int t = i >> 16;
    int dir = r >> 10, b = r & 1023;
    int tt = t;
    if (dir) {
        int ri = len[b] - 1 - t;
        tt = ri < 0 ? 0 : (ri > T_ - 1 ? T_ - 1 : ri);
    }
    float4 v = *(const float4*)(xenc + ((size_t)b * T_ + tt) * 128 + c4);
    ushort4 o = { f2bf(v.x), f2bf(v.y), f2bf(v.z), f2bf(v.w) };
    *(ushort4*)(xe + ((size_t)t * 2048 + r) * 128 + c4) = o;
}

__global__ void pack_xdec(const float* __restrict__ emb, const int* __restrict__ tokens,
                          ushort* __restrict__ xd) {
    int i = blockIdx.x * 256 + threadIdx.x;   // 15*1024*32
    if (i >= 15 * 1024 * 32) return;
    int c4 = (i & 31) * 4;
    int b = (i >> 5) & 1023;
    int t = i >> 15;
    ushort4 o = { 0, 0, 0, 0 };
    if (t > 0) {
        int tok = tokens[(size_t)b * T_ + (t - 1)];
        float4 v = *(const float4*)(emb + (size_t)tok * 128 + c4);
        o = ushort4{ f2bf(v.x), f2bf(v.y), f2bf(v.z), f2bf(v.w) };
    }
    *(ushort4*)(xd + ((size_t)t * 1024 + b) * 128 + c4) = o;
}

__global__ void init_zero(float* cenc, float* cdec, ushort* hA, float* accs) {
    int i = blockIdx.x * 256 + threadIdx.x;
    if (i < 2 * 1024 * 1024) { cenc[i] = 0.0f; hA[i] = 0; }
    if (i < 1024 * 1024) cdec[i] = 0.0f;
    if (i < 8) accs[i] = 0.0f;
}

__global__ void latent_ew(const float* __restrict__ ml, const float* __restrict__ bmv,
                          const float* __restrict__ blv, const float* __restrict__ eps,
                          ushort* __restrict__ zp, float* __restrict__ klacc) {
    int idx = blockIdx.x * 256 + threadIdx.x;
    int b = idx >> 7, l = idx & (L_ - 1);
    float mean = ml[(size_t)b * 256 + l] + bmv[l];
    float logv = ml[(size_t)b * 256 + L_ + l] + blv[l];
    zp[idx] = f2bf(eps[idx] * expf(0.5f * logv) + mean);
    float part = 1.0f + logv - mean * mean - expf(logv);
    for (int off = 32; off; off >>= 1) part += __shfl_down(part, off);
    __shared__ float s[4];
    int lane = threadIdx.x & 63, wv = threadIdx.x >> 6;
    if (lane == 0) s[wv] = part;
    __syncthreads();
    if (threadIdx.x == 0) atomicAdd(klacc, s[0] + s[1] + s[2] + s[3]);
}

__global__ void finalize_k(const float* accs, float* out) {
    if (threadIdx.x == 0 && blockIdx.x == 0) {
        float kl = -0.5f * accs[3] / (float)B_;
        float amino = accs[0] / (float)B_;
        out[0] = amino + 0.1f * kl;
        out[1] = amino;
        out[2] = kl;
        out[3] = accs[1] / accs[2];
    }
}

// ================= host =================
extern "C" void kernel_launch(void* const* d_in, const int* in_sizes, int n_in,
                              void* d_out, int out_size, void* d_ws, size_t ws_size,
                              hipStream_t stream) {
    (void)in_sizes; (void)n_in; (void)out_size; (void)ws_size;
    const float* x_enc  = (const float*)d_in[0];
    const int*   tokens = (const int*)d_in[1];
    const int*   lengths= (const int*)d_in[2];
    const float* eps    = (const float*)d_in[3];
    const float* emb    = (const float*)d_in[4];
    const float* Wih_f  = (const float*)d_in[5];
    const float* Whh_f  = (const float*)d_in[6];
    const float* b_f    = (const float*)d_in[7];
    const float* Wih_b  = (const float*)d_in[8];
    const float* Whh_b  = (const float*)d_in[9];
    const float* b_b    = (const float*)d_in[10];
    const float* Wm     = (const float*)d_in[11];
    const float* bm     = (const float*)d_in[12];
    const float* Wl     = (const float*)d_in[13];
    const float* bl     = (const float*)d_in[14];
    const float* Wz     = (const float*)d_in[15];
    const float* bz     = (const float*)d_in[16];
    const float* Wi     = (const float*)d_in[17];
    const float* bi     = (const float*)d_in[18];
    const float* Wo     = (const float*)d_in[19];
    const float* bo     = (const float*)d_in[20];
    const float* Wfm    = (const float*)d_in[21];
    const float* bf     = (const float*)d_in[22];
    const float* Wg     = (const float*)d_in[23];
    const float* bg     = (const float*)d_in[24];
    const float* W1     = (const float*)d_in[25];
    const float* b1     = (const float*)d_in[26];
    const float* W2     = (const float*)d_in[27];
    const float* b2     = (const float*)d_in[28];

    float*  cenc = (float*)d_ws;                    // 2M f32
    float*  cdec = cenc + 2 * 1024 * 1024;          // 1M f32
    float*  ml   = cdec + 1024 * 1024;              // 256K f32
    float*  accs = ml + 1024 * 256;                 // 8 (+pad 64)
    ushort* hA   = (ushort*)(accs + 64);            // 2M
    ushort* hB   = hA + 2 * 1024 * 1024;
    ushort* hdA  = hB + 2 * 1024 * 1024;            // 1M
    ushort* hdB  = hdA + 1024 * 1024;
    ushort* h1A  = hdB + 1024 * 1024;               // 1M
    ushort* h1B  = h1A + 1024 * 1024;
    ushort* zp   = h1B + 1024 * 1024;               // 128K
    ushort* xe   = zp + 1024 * 128;                 // 15*2048*128
    ushort* xd   = xe + 15 * 2048 * 128;            // 15*1024*128
    ushort* Wenc = xd + 15 * 1024 * 128;            // 2*4096*1152
    ushort* Wdec = Wenc + 2 * 4096 * 1152;          // 4096*1152
    ushort* W1p  = Wdec + 4096 * 1152;              // 1024*1280
    ushort* Wml  = W1p + 1024 * 1280;               // 256*2048
    ushort* Wzp  = Wml + 256 * 2048;                // 1024*128
    ushort* W2p  = Wzp + 1024 * 128;                // 128*1024

    init_zero<<<8192, 256, 0, stream>>>(cenc, cdec, hA, accs);
    pack_gates_enc<<<9216, 256, 0, stream>>>(Wih_f, Whh_f, Wih_b, Whh_b, Wenc);
    pack_gates_dec<<<4608, 256, 0, stream>>>(Wi, Wo, Wfm, Wg, Wdec);
    pack_cols<<<1280, 256, 0, stream>>>(W1, 1280, W1p, 1280, 0, 1024, 1280);
    pack_cols<<<256, 256, 0, stream>>>(Wm, 2048, Wml, 2048, 0, L_, 2048);
    pack_cols<<<256, 256, 0, stream>>>(Wl, 2048, Wml + L_ * 2048, 2048, 0, L_, 2048);
    pack_cols<<<128, 256, 0, stream>>>(Wz, L_, Wzp, L_, 0, H_, L_);
    pack_w2<<<128, 256, 0, stream>>>(W2, W2p);
    pack_xenc<<<3840, 256, 0, stream>>>(x_enc, lengths, xe);
    pack_xdec<<<1920, 256, 0, stream>>>(emb, tokens, xd);

    // ---- encoder ----
    {
        const ushort* hc = hA; ushort* hn = hB;
        for (int t = 0; t < T_; ++t) {
            gemm_ring<<<dim3(32, 16), 256, 0, stream>>>(
                ALdEnc{ xe + (size_t)t * 2048 * 128, hc, 0 }, WLdEnc{ Wenc },
                EpiEnc{ b_f, b_b, lengths, t, cenc, hc, hn });
            const ushort* tmp = hn; hn = (ushort*)hc; hc = tmp;
        }
        gemm_ring<<<dim3(2, 8), 256, 0, stream>>>(
            ALdHid{ hc, 0 }, WLdPlain{ Wml, 2048 }, EpiStoreF32{ ml, 256 });
    }
    latent_ew<<<512, 256, 0, stream>>>(ml, bm, bl, eps, zp, &accs[3]);
    gemm_ring<<<dim3(8, 8), 256, 0, stream>>>(
        ALdPlain{ zp, 128, 128, 0 }, WLdPlain{ Wzp, 128 }, EpiBiasBf16{ hdA, bz });

    // ---- decoder: scores(t-1) fused as extra bn segment ----
    {
        const ushort* dc = hdA; ushort* dn = hdB;
        for (int t = 0; t < T_; ++t) {
            ushort* h1c = (t & 1) ? h1B : h1A;
            const ushort* h1p = (t & 1) ? h1A : h1B;
            dim3 grid(t == 0 ? 40 : 41, 8);
            gemm_ring<<<grid, 256, 0, stream>>>(
                ALdDec{ xd + (size_t)t * 1024 * 128, dc, zp, h1p, 0 },
                WLdDec{ Wdec, W1p, W2p },
                EpiDec{ bi, bo, bf, bg, b1, b2, cdec, dn, h1c, tokens, lengths, t, accs });
            const ushort* tmp = dn; dn = (ushort*)dc; dc = tmp;
        }
        const ushort* h1p14 = ((T_ - 1) & 1) ? h1B : h1A;  // hid1 written at t=14
        gemm_ring<<<dim3(1, 8), 256, 0, stream>>>(
            ALdDec{ xd, dc, zp, h1p14, 5120 },
            WLdDec{ Wdec, W1p, W2p },
            EpiDec{ bi, bo, bf, bg, b1, b2, cdec, hdB, h1B, tokens, lengths, T_, accs });
    }

    finalize_k<<<1, 64, 0, stream>>>(accs, (float*)d_out);
}

// Round 7
// 1288.706 us; speedup vs baseline: 1.7271x; 1.3385x over previous
//
#include <hip/hip_runtime.h>
#include <math.h>

#define B_ 1024
#define T_ 15
#define E_ 128
#define H_ 1024
#define L_ 128
#define V_ 21

typedef __attribute__((ext_vector_type(8))) short bf16x8;
typedef __attribute__((ext_vector_type(4))) float f32x4;

// overflow-safe fast sigmoid / tanh (v_exp_f32 path)
__device__ __forceinline__ float sigf(float x) { return 1.0f / (1.0f + __expf(-x)); }
__device__ __forceinline__ float tanhfast(float x) {
    float t = __expf(-2.0f * fabsf(x));          // in (0,1], never overflows
    float r = (1.0f - t) / (1.0f + t);
    return copysignf(r, x);
}

__device__ __forceinline__ ushort f2bf(float f) {
    unsigned u = __float_as_uint(f);
    u += 0x7fffu + ((u >> 16) & 1u);
    return (ushort)(u >> 16);
}

__device__ __forceinline__ void gl_lds16(const ushort* g, ushort* l) {
    __builtin_amdgcn_global_load_lds(
        (const __attribute__((address_space(1))) void*)g,
        (__attribute__((address_space(3))) void*)l, 16, 0, 0);
}

// ============ double-buffered bf16 MFMA GEMM, BK=64 (R4 discipline) ============
// Tile 128x128, BK=64 as two 32-col sub-tiles [ch][128 rows][32] (same fragment
// layout + bank behavior as the proven BK=32 version). 4 waves (2x2), each wave
// 64x64 = 4x4 frags of 16x16x32, 2 MFMA k-steps per tile. Staging: R4's
// coalesced map (srow=tid>>2, scol=(tid&3)*8, 64B/row requests, linear LDS dest).
// Sync: __syncthreads at iter end (compiler drains vmcnt) — prefetch for t+1 is
// issued BEFORE the ds_reads, so ds_read+2xMFMA covers its latency.
template <class ALd, class WLd, class Epi>
__global__ __launch_bounds__(256) void gemm_dbuf(ALd al, WLd wl, Epi ep) {
    __shared__ ushort As[2 * 8192];   // [buf][ch*4096 + row*32 + c]
    __shared__ ushort Ws[2 * 8192];
    const int tid = threadIdx.x;
    const int lane = tid & 63;
    const int w = tid >> 6;
    const int wr = w >> 1, wc = w & 1;
    const int bn = blockIdx.x * 128 + al.bn0;
    const int bm = blockIdx.y * 128;
    const int srow = tid >> 2;           // 0..63
    const int scol = (tid & 3) * 8;      // 0,8,16,24
    const int K = al.kdim(bn);
    const int nt = K >> 6;               // BK=64 tiles

    auto STAGE = [&](int ti, int buf) {
        const int k0 = ti * 64;
        ushort* ab = As + buf * 8192 + w * 512;
        ushort* wb = Ws + buf * 8192 + w * 512;
#pragma unroll
        for (int ch = 0; ch < 2; ++ch) {
            const int kc = k0 + ch * 32 + scol;
            gl_lds16(al.addr(bn, bm + srow, kc),      ab + ch * 4096);
            gl_lds16(al.addr(bn, bm + 64 + srow, kc), ab + ch * 4096 + 2048);
            gl_lds16(wl.addr(bm, bn + srow, kc),      wb + ch * 4096);
            gl_lds16(wl.addr(bm, bn + 64 + srow, kc), wb + ch * 4096 + 2048);
        }
    };

    f32x4 acc[4][4];
#pragma unroll
    for (int m = 0; m < 4; ++m)
#pragma unroll
        for (int n = 0; n < 4; ++n) acc[m][n] = (f32x4)0.0f;

    STAGE(0, 0);
    __syncthreads();                     // drain prologue loads

    const int frow = lane & 15, fk = (lane >> 4) * 8;
    const int foff = (wr * 64 + frow) * 32 + fk;
    const int goff = (wc * 64 + frow) * 32 + fk;

    for (int t = 0; t < nt; ++t) {
        if (t + 1 < nt) STAGE(t + 1, (t + 1) & 1);   // issue early: covered by reads+MFMA
        const ushort* asb = As + (t & 1) * 8192;
        const ushort* wsb = Ws + (t & 1) * 8192;
#pragma unroll
        for (int ch = 0; ch < 2; ++ch) {
            const ushort* asp = asb + ch * 4096 + foff;
            const ushort* bsp = wsb + ch * 4096 + goff;
            bf16x8 af[4], bw[4];
#pragma unroll
            for (int m = 0; m < 4; ++m) af[m] = *(const bf16x8*)(asp + m * 512);
#pragma unroll
            for (int n = 0; n < 4; ++n) bw[n] = *(const bf16x8*)(bsp + n * 512);
#pragma unroll
            for (int m = 0; m < 4; ++m)
#pragma unroll
                for (int n = 0; n < 4; ++n)
                    acc[m][n] = __builtin_amdgcn_mfma_f32_16x16x32_bf16(af[m], bw[n], acc[m][n], 0, 0, 0);
        }
        __syncthreads();                 // drains vmcnt: tile t+1 ready; buf t reusable
    }
    ep(bm, bn, wr, wc, lane, acc);
}

// ================= loaders =================
struct ALdEnc {  // rows: dir*1024+b ; cols: [x_t(128) | h(1024)]
    const ushort* xe; const ushort* h; int bn0;
    __device__ int kdim(int) const { return 1152; }
    __device__ const ushort* addr(int, int row, int k) const {
        return (k < 128) ? xe + (size_t)row * 128 + k
                         : h + (size_t)row * 1024 + (k - 128);
    }
};
struct WLdEnc {  // [2][4096][1152] gate-interleaved, dir = bm>>10
    const ushort* W;
    __device__ const ushort* addr(int bm, int n, int k) const {
        return W + ((size_t)(bm >> 10) * 4096 + n) * 1152 + k;
    }
};
struct ALdDec {  // rows: b ; cols: [x_t | h | z]; bn>=5120 -> hid1prev (K=1024)
    const ushort* xd; const ushort* h; const ushort* z;
    const ushort* hid1prev; int bn0;
    __device__ int kdim(int bn) const {
        return bn < 4096 ? 1152 : (bn < 5120 ? 1280 : 1024);
    }
    __device__ const ushort* addr(int bn, int row, int k) const {
        if (bn >= 5120) return hid1prev + (size_t)row * 1024 + k;
        if (k < 128) return xd + (size_t)row * 128 + k;
        if (k < 1152) return h + (size_t)row * 1024 + (k - 128);
        return z + (size_t)row * 128 + (k - 1152);
    }
};
struct WLdDec {  // [4096][1152] gates | [1024][1280] W1 | [128][1024] W2pad
    const ushort* Wg4; const ushort* W1; const ushort* W2p;
    __device__ const ushort* addr(int, int n, int k) const {
        if (n < 4096) return Wg4 + (size_t)n * 1152 + k;
        if (n < 5120) return W1 + (size_t)(n - 4096) * 1280 + k;
        return W2p + (size_t)(n - 5120) * 1024 + k;
    }
};
struct ALdHid {  // hidden = [h_f | h_b]
    const ushort* hF; int bn0;
    __device__ int kdim(int) const { return 2048; }
    __device__ const ushort* addr(int, int row, int k) const {
        return hF + ((size_t)((k >> 10) << 10) + row) * 1024 + (k & 1023);
    }
};
struct ALdPlain {
    const ushort* A; int ld; int K; int bn0;
    __device__ int kdim(int) const { return K; }
    __device__ const ushort* addr(int, int row, int k) const { return A + (size_t)row * ld + k; }
};
struct WLdPlain {
    const ushort* W; int ld;
    __device__ const ushort* addr(int, int n, int k) const { return W + (size_t)n * ld + k; }
};

// ================= epilogues =================
struct EpiEnc {  // fused encoder LSTM cell, gate-interleaved: frag n = gate n (i,f,g,o)
    const float* b_f; const float* b_b; const int* len; int t;
    float* c; const ushort* hc; ushort* hn;
    __device__ void operator()(int bm, int bn, int wr, int wc, int lane,
                               f32x4 (&acc)[4][4]) const {
        const int j = ((bn >> 6) + wc) * 16 + (lane & 15);
        const int rbase = bm + wr * 64 + ((lane >> 4) << 2);
#pragma unroll
        for (int m = 0; m < 4; ++m) {
#pragma unroll
            for (int r = 0; r < 4; ++r) {
                const int row = rbase + m * 16 + r;
                const int b = row & 1023;
                const float* bias = (row >> 10) ? b_b : b_f;
                const size_t o = (size_t)row * 1024 + j;
                if (t < len[b]) {
                    float gi = acc[m][0][r] + bias[j];
                    float gf = acc[m][1][r] + bias[1024 + j];
                    float gg = acc[m][2][r] + bias[2048 + j];
                    float go = acc[m][3][r] + bias[3072 + j];
                    float nc = sigf(gf) * c[o] + sigf(gi) * tanhfast(gg);
                    c[o] = nc;
                    hn[o] = f2bf(sigf(go) * tanhfast(nc));
                } else {
                    hn[o] = hc[o];
                }
            }
        }
    }
};

struct EpiDec {
    const float *bi, *bo, *bfv, *bg, *b1, *b2;
    float* c; ushort* hn; ushort* hid1cur;
    const int* tokens; const int* len; int t;
    float* accs;
    __device__ void operator()(int bm, int bn, int wr, int wc, int lane,
                               f32x4 (&acc)[4][4]) const {
        const int rbase = bm + wr * 64 + ((lane >> 4) << 2);
        if (bn < 4096) {            // fused decoder LSTM cell (i,o,f,g)
            const int j = ((bn >> 6) + wc) * 16 + (lane & 15);
#pragma unroll
            for (int m = 0; m < 4; ++m) {
#pragma unroll
                for (int r = 0; r < 4; ++r) {
                    const int b = rbase + m * 16 + r;
                    const size_t o = (size_t)b * 1024 + j;
                    float gi = sigf(acc[m][0][r] + bi[j]);
                    float go = sigf(acc[m][1][r] + bo[j]);
                    float gf = sigf(acc[m][2][r] + bfv[j]);
                    float gg = tanhfast(acc[m][3][r] + bg[j]);
                    float nc = gf * c[o] + gi * gg;
                    c[o] = nc;
                    hn[o] = f2bf(go * tanhfast(nc));
                }
            }
        } else if (bn < 5120) {     // hid1 = relu(ah@W1^T + b1), bf16
            const int cb = (bn - 4096) + wc * 64;
#pragma unroll
            for (int m = 0; m < 4; ++m)
#pragma unroll
                for (int n = 0; n < 4; ++n) {
                    const int col = cb + n * 16 + (lane & 15);
#pragma unroll
                    for (int r = 0; r < 4; ++r)
                        hid1cur[(size_t)(rbase + m * 16 + r) * 1024 + col] =
                            f2bf(fmaxf(acc[m][n][r] + b1[col], 0.0f));
                }
        } else {                    // scores(t-1): CE/argmax, wave-parallel
            if (wc != 0) return;
            const int ts = t - 1;
            const int col0 = lane & 15;
            const bool v1ok = col0 < (V_ - 16);   // cols 16..20
            const float b2v0 = b2[col0];
            const float b2v1 = v1ok ? b2[16 + col0] : 0.0f;
            float ce_loc = 0.f, cor_loc = 0.f, msk_loc = 0.f;
#pragma unroll
            for (int m = 0; m < 4; ++m) {
#pragma unroll
                for (int r = 0; r < 4; ++r) {
                    const int b = rbase + m * 16 + r;
                    const int lb = len[b];
                    float v0 = acc[m][0][r] + b2v0;
                    float v1 = v1ok ? (acc[m][1][r] + b2v1) : -1e30f;
                    float mv; int mi;
                    if (v1 > v0) { mv = v1; mi = 16 + col0; } else { mv = v0; mi = col0; }
#pragma unroll
                    for (int s = 1; s < 16; s <<= 1) {
                        float ov = __shfl_xor(mv, s);
                        int oi = __shfl_xor(mi, s);
                        if (ov > mv || (ov == mv && oi < mi)) { mv = ov; mi = oi; }
                    }
                    float se = expf(v0 - mv) + (v1ok ? expf(v1 - mv) : 0.0f);
#pragma unroll
                    for (int s = 1; s < 16; s <<= 1) se += __shfl_xor(se, s);
                    float lse = mv + logf(se);
                    int tgt = (ts < lb) ? tokens[b * T_ + ts] : 0;
                    int srcl = (lane & 48) | (tgt & 15);
                    float sv0 = __shfl(v0, srcl);
                    float sv1 = __shfl(v1, srcl);
                    float stgt = (tgt < 16) ? sv0 : sv1;
                    if (ts <= lb && col0 == 0) {
                        ce_loc += lse - stgt;
                        cor_loc += (mi == tgt) ? 1.0f : 0.0f;
                        msk_loc += 1.0f;
                    }
                }
            }
            float ce = __shfl(ce_loc, 0) + __shfl(ce_loc, 16) + __shfl(ce_loc, 32) + __shfl(ce_loc, 48);
            float co = __shfl(cor_loc, 0) + __shfl(cor_loc, 16) + __shfl(cor_loc, 32) + __shfl(cor_loc, 48);
            float mk = __shfl(msk_loc, 0) + __shfl(msk_loc, 16) + __shfl(msk_loc, 32) + __shfl(msk_loc, 48);
            if (lane == 0) {
                atomicAdd(&accs[0], ce);
                atomicAdd(&accs[1], co);
                atomicAdd(&accs[2], mk);
            }
        }
    }
};

struct EpiStoreF32 {
    float* out; int ldc;
    __device__ void operator()(int bm, int bn, int wr, int wc, int lane,
                               f32x4 (&acc)[4][4]) const {
        const int rbase = bm + wr * 64 + ((lane >> 4) << 2);
        const int cbase = bn + wc * 64 + (lane & 15);
#pragma unroll
        for (int m = 0; m < 4; ++m)
#pragma unroll
            for (int n = 0; n < 4; ++n)
#pragma unroll
                for (int r = 0; r < 4; ++r)
                    out[(size_t)(rbase + m * 16 + r) * ldc + cbase + n * 16] = acc[m][n][r];
    }
};
struct EpiBiasBf16 {
    ushort* out; const float* bias;
    __device__ void operator()(int bm, int bn, int wr, int wc, int lane,
                               f32x4 (&acc)[4][4]) const {
        const int rbase = bm + wr * 64 + ((lane >> 4) << 2);
        const int cbase = bn + wc * 64 + (lane & 15);
#pragma unroll
        for (int m = 0; m < 4; ++m)
#pragma unroll
            for (int n = 0; n < 4; ++n) {
                const int col = cbase + n * 16;
#pragma unroll
                for (int r = 0; r < 4; ++r)
                    out[(size_t)(rbase + m * 16 + r) * 1024 + col] = f2bf(acc[m][n][r] + bias[col]);
            }
    }
};

// ================= packing / elementwise =================
__global__ void pack_cols(const float* __restrict__ src, int src_ld,
                          ushort* __restrict__ dst, int dst_ld, int dcol0,
                          int rows, int cols) {
    int i = blockIdx.x * 256 + threadIdx.x;
    int c4cnt = cols >> 2;
    if (i >= rows * c4cnt) return;
    int r = i / c4cnt, c4 = (i - r * c4cnt) * 4;
    float4 v = *(const float4*)(src + (size_t)r * src_ld + c4);
    ushort4 o = { f2bf(v.x), f2bf(v.y), f2bf(v.z), f2bf(v.w) };
    *(ushort4*)(dst + (size_t)r * dst_ld + dcol0 + c4) = o;
}

__global__ void pack_gates_enc(const float* __restrict__ Wih_f, const float* __restrict__ Whh_f,
                               const float* __restrict__ Wih_b, const float* __restrict__ Whh_b,
                               ushort* __restrict__ dst) {
    int i = blockIdx.x * 256 + threadIdx.x;   // 2*4096*288
    if (i >= 2 * 4096 * 288) return;
    int c4 = (i % 288) * 4;
    int p = (i / 288) & 4095;
    int dir = i / (288 * 4096);
    int j = ((p >> 6) << 4) + (p & 15);
    int g = (p >> 4) & 3;
    int srow = g * 1024 + j;
    float4 v;
    if (c4 < 128) {
        const float* s = dir ? Wih_b : Wih_f;
        v = *(const float4*)(s + (size_t)srow * 128 + c4);
    } else {
        const float* s = dir ? Whh_b : Whh_f;
        v = *(const float4*)(s + (size_t)srow * 1024 + (c4 - 128));
    }
    ushort4 o = { f2bf(v.x), f2bf(v.y), f2bf(v.z), f2bf(v.w) };
    *(ushort4*)(dst + ((size_t)dir * 4096 + p) * 1152 + c4) = o;
}

__global__ void pack_gates_dec(const float* __restrict__ Wi, const float* __restrict__ Wo,
                               const float* __restrict__ Wf, const float* __restrict__ Wg,
                               ushort* __restrict__ dst) {
    int i = blockIdx.x * 256 + threadIdx.x;   // 4096*288
    if (i >= 4096 * 288) return;
    int c4 = (i % 288) * 4;
    int p = i / 288;
    int j = ((p >> 6) << 4) + (p & 15);
    int g = (p >> 4) & 3;
    const float* s = (g == 0) ? Wi : (g == 1) ? Wo : (g == 2) ? Wf : Wg;
    float4 v = *(const float4*)(s + (size_t)j * 1152 + c4);
    ushort4 o = { f2bf(v.x), f2bf(v.y), f2bf(v.z), f2bf(v.w) };
    *(ushort4*)(dst + (size_t)p * 1152 + c4) = o;
}

__global__ void pack_w2(const float* __restrict__ W2, ushort* __restrict__ dst) {
    int i = blockIdx.x * 256 + threadIdx.x;   // 128*256
    if (i >= 128 * 256) return;
    int r = i >> 8, c4 = (i & 255) * 4;
    ushort4 o = { 0, 0, 0, 0 };
    if (r < V_) {
        float4 v = *(const float4*)(W2 + (size_t)r * 1024 + c4);
        o = ushort4{ f2bf(v.x), f2bf(v.y), f2bf(v.z), f2bf(v.w) };
    }
    *(ushort4*)(dst + (size_t)r * 1024 + c4) = o;
}

__global__ void pack_xenc(const float* __restrict__ xenc, const int* __restrict__ len,
                          ushort* __restrict__ xe) {
    int i = blockIdx.x * 256 + threadIdx.x;   // 15*2048*32
    if (i >= 15 * 2048 * 32) return;
    int c4 = (i & 31) * 4;
    int r = (i >> 5) & 2047;
    int t = i >> 16;
    int dir = r >> 10, b = r & 1023;
    int tt = t;
    if (dir) {
        int ri = len[b] - 1 - t;
        tt = ri < 0 ? 0 : (ri > T_ - 1 ? T_ - 1 : ri);
    }
    float4 v = *(const float4*)(xenc + ((size_t)b * T_ + tt) * 128 + c4);
    ushort4 o = { f2bf(v.x), f2bf(v.y), f2bf(v.z), f2bf(v.w) };
    *(ushort4*)(xe + ((size_t)t * 2048 + r) * 128 + c4) = o;
}

__global__ void pack_xdec(const float* __restrict__ emb, const int* __restrict__ tokens,
                          ushort* __restrict__ xd) {
    int i = blockIdx.x * 256 + threadIdx.x;   // 15*1024*32
    if (i >= 15 * 1024 * 32) return;
    int c4 = (i & 31) * 4;
    int b = (i >> 5) & 1023;
    int t = i >> 15;
    ushort4 o = { 0, 0, 0, 0 };
    if (t > 0) {
        int tok = tokens[(size_t)b * T_ + (t - 1)];
        float4 v = *(const float4*)(emb + (size_t)tok * 128 + c4);
        o = ushort4{ f2bf(v.x), f2bf(v.y), f2bf(v.z), f2bf(v.w) };
    }
    *(ushort4*)(xd + ((size_t)t * 1024 + b) * 128 + c4) = o;
}

__global__ void init_zero(float* cenc, float* cdec, ushort* hA, float* accs) {
    int i = blockIdx.x * 256 + threadIdx.x;
    if (i < 2 * 1024 * 1024) { cenc[i] = 0.0f; hA[i] = 0; }
    if (i < 1024 * 1024) cdec[i] = 0.0f;
    if (i < 8) accs[i] = 0.0f;
}

__global__ void latent_ew(const float* __restrict__ ml, const float* __restrict__ bmv,
                          const float* __restrict__ blv, const float* __restrict__ eps,
                          ushort* __restrict__ zp, float* __restrict__ klacc) {
    int idx = blockIdx.x * 256 + threadIdx.x;
    int b = idx >> 7, l = idx & (L_ - 1);
    float mean = ml[(size_t)b * 256 + l] + bmv[l];
    float logv = ml[(size_t)b * 256 + L_ + l] + blv[l];
    zp[idx] = f2bf(eps[idx] * expf(0.5f * logv) + mean);
    float part = 1.0f + logv - mean * mean - expf(logv);
    for (int off = 32; off; off >>= 1) part += __shfl_down(part, off);
    __shared__ float s[4];
    int lane = threadIdx.x & 63, wv = threadIdx.x >> 6;
    if (lane == 0) s[wv] = part;
    __syncthreads();
    if (threadIdx.x == 0) atomicAdd(klacc, s[0] + s[1] + s[2] + s[3]);
}

__global__ void finalize_k(const float* accs, float* out) {
    if (threadIdx.x == 0 && blockIdx.x == 0) {
        float kl = -0.5f * accs[3] / (float)B_;
        float amino = accs[0] / (float)B_;
        out[0] = amino + 0.1f * kl;
        out[1] = amino;
        out[2] = kl;
        out[3] = accs[1] / accs[2];
    }
}

// ================= host =================
extern "C" void kernel_launch(void* const* d_in, const int* in_sizes, int n_in,
                              void* d_out, int out_size, void* d_ws, size_t ws_size,
                              hipStream_t stream) {
    (void)in_sizes; (void)n_in; (void)out_size; (void)ws_size;
    const float* x_enc  = (const float*)d_in[0];
    const int*   tokens = (const int*)d_in[1];
    const int*   lengths= (const int*)d_in[2];
    const float* eps    = (const float*)d_in[3];
    const float* emb    = (const float*)d_in[4];
    const float* Wih_f  = (const float*)d_in[5];
    const float* Whh_f  = (const float*)d_in[6];
    const float* b_f    = (const float*)d_in[7];
    const float* Wih_b  = (const float*)d_in[8];
    const float* Whh_b  = (const float*)d_in[9];
    const float* b_b    = (const float*)d_in[10];
    const float* Wm     = (const float*)d_in[11];
    const float* bm     = (const float*)d_in[12];
    const float* Wl     = (const float*)d_in[13];
    const float* bl     = (const float*)d_in[14];
    const float* Wz     = (const float*)d_in[15];
    const float* bz     = (const float*)d_in[16];
    const float* Wi     = (const float*)d_in[17];
    const float* bi     = (const float*)d_in[18];
    const float* Wo     = (const float*)d_in[19];
    const float* bo     = (const float*)d_in[20];
    const float* Wfm    = (const float*)d_in[21];
    const float* bf     = (const float*)d_in[22];
    const float* Wg     = (const float*)d_in[23];
    const float* bg     = (const float*)d_in[24];
    const float* W1     = (const float*)d_in[25];
    const float* b1     = (const float*)d_in[26];
    const float* W2     = (const float*)d_in[27];
    const float* b2     = (const float*)d_in[28];

    float*  cenc = (float*)d_ws;                    // 2M f32
    float*  cdec = cenc + 2 * 1024 * 1024;          // 1M f32
    float*  ml   = cdec + 1024 * 1024;              // 256K f32
    float*  accs = ml + 1024 * 256;                 // 8 (+pad 64)
    ushort* hA   = (ushort*)(accs + 64);            // 2M
    ushort* hB   = hA + 2 * 1024 * 1024;
    ushort* hdA  = hB + 2 * 1024 * 1024;            // 1M
    ushort* hdB  = hdA + 1024 * 1024;
    ushort* h1A  = hdB + 1024 * 1024;               // 1M
    ushort* h1B  = h1A + 1024 * 1024;
    ushort* zp   = h1B + 1024 * 1024;               // 128K
    ushort* xe   = zp + 1024 * 128;                 // 15*2048*128
    ushort* xd   = xe + 15 * 2048 * 128;            // 15*1024*128
    ushort* Wenc = xd + 15 * 1024 * 128;            // 2*4096*1152
    ushort* Wdec = Wenc + 2 * 4096 * 1152;          // 4096*1152
    ushort* W1p  = Wdec + 4096 * 1152;              // 1024*1280
    ushort* Wml  = W1p + 1024 * 1280;               // 256*2048
    ushort* Wzp  = Wml + 256 * 2048;                // 1024*128
    ushort* W2p  = Wzp + 1024 * 128;                // 128*1024

    init_zero<<<8192, 256, 0, stream>>>(cenc, cdec, hA, accs);
    pack_gates_enc<<<9216, 256, 0, stream>>>(Wih_f, Whh_f, Wih_b, Whh_b, Wenc);
    pack_gates_dec<<<4608, 256, 0, stream>>>(Wi, Wo, Wfm, Wg, Wdec);
    pack_cols<<<1280, 256, 0, stream>>>(W1, 1280, W1p, 1280, 0, 1024, 1280);
    pack_cols<<<256, 256, 0, stream>>>(Wm, 2048, Wml, 2048, 0, L_, 2048);
    pack_cols<<<256, 256, 0, stream>>>(Wl, 2048, Wml + L_ * 2048, 2048, 0, L_, 2048);
    pack_cols<<<128, 256, 0, stream>>>(Wz, L_, Wzp, L_, 0, H_, L_);
    pack_w2<<<128, 256, 0, stream>>>(W2, W2p);
    pack_xenc<<<3840, 256, 0, stream>>>(x_enc, lengths, xe);
    pack_xdec<<<1920, 256, 0, stream>>>(emb, tokens, xd);

    // ---- encoder ----
    {
        const ushort* hc = hA; ushort* hn = hB;
        for (int t = 0; t < T_; ++t) {
            gemm_dbuf<<<dim3(32, 16), 256, 0, stream>>>(
                ALdEnc{ xe + (size_t)t * 2048 * 128, hc, 0 }, WLdEnc{ Wenc },
                EpiEnc{ b_f, b_b, lengths, t, cenc, hc, hn });
            const ushort* tmp = hn; hn = (ushort*)hc; hc = tmp;
        }
        gemm_dbuf<<<dim3(2, 8), 256, 0, stream>>>(
            ALdHid{ hc, 0 }, WLdPlain{ Wml, 2048 }, EpiStoreF32{ ml, 256 });
    }
    latent_ew<<<512, 256, 0, stream>>>(ml, bm, bl, eps, zp, &accs[3]);
    gemm_dbuf<<<dim3(8, 8), 256, 0, stream>>>(
        ALdPlain{ zp, 128, 128, 0 }, WLdPlain{ Wzp, 128 }, EpiBiasBf16{ hdA, bz });

    // ---- decoder: scores(t-1) fused as extra bn segment ----
    {
        const ushort* dc = hdA; ushort* dn = hdB;
        for (int t = 0; t < T_; ++t) {
            ushort* h1c = (t & 1) ? h1B : h1A;
            const ushort* h1p = (t & 1) ? h1A : h1B;
            dim3 grid(t == 0 ? 40 : 41, 8);
            gemm_dbuf<<<grid, 256, 0, stream>>>(
                ALdDec{ xd + (size_t)t * 1024 * 128, dc, zp, h1p, 0 },
                WLdDec{ Wdec, W1p, W2p },
                EpiDec{ bi, bo, bf, bg, b1, b2, cdec, dn, h1c, tokens, lengths, t, accs });
            const ushort* tmp = dn; dn = (ushort*)dc; dc = tmp;
        }
        const ushort* h1p14 = ((T_ - 1) & 1) ? h1B : h1A;  // hid1 written at t=14
        gemm_dbuf<<<dim3(1, 8), 256, 0, stream>>>(
            ALdDec{ xd, dc, zp, h1p14, 5120 },
            WLdDec{ Wdec, W1p, W2p },
            EpiDec{ bi, bo, bf, bg, b1, b2, cdec, hdB, h1B, tokens, lengths, T_, accs });
    }

    finalize_k<<<1, 64, 0, stream>>>(accs, (float*)d_out);
}

// Round 8
// 1252.235 us; speedup vs baseline: 1.7774x; 1.0291x over previous
//
#include <hip/hip_runtime.h>
#include <math.h>

#define B_ 1024
#define T_ 15
#define E_ 128
#define H_ 1024
#define L_ 128
#define V_ 21

typedef __attribute__((ext_vector_type(8))) short bf16x8;
typedef __attribute__((ext_vector_type(4))) float f32x4;

// overflow-safe fast sigmoid / tanh (v_exp_f32 path)
__device__ __forceinline__ float sigf(float x) { return 1.0f / (1.0f + __expf(-x)); }
__device__ __forceinline__ float tanhfast(float x) {
    float t = __expf(-2.0f * fabsf(x));          // in (0,1], never overflows
    float r = (1.0f - t) / (1.0f + t);
    return copysignf(r, x);
}

__device__ __forceinline__ ushort f2bf(float f) {
    unsigned u = __float_as_uint(f);
    u += 0x7fffu + ((u >> 16) & 1u);
    return (ushort)(u >> 16);
}
__device__ __forceinline__ float bf2f(ushort u) {
    return __uint_as_float((unsigned)u << 16);
}

__device__ __forceinline__ void gl_lds16(const ushort* g, ushort* l) {
    __builtin_amdgcn_global_load_lds(
        (const __attribute__((address_space(1))) void*)g,
        (__attribute__((address_space(3))) void*)l, 16, 0, 0);
}

// ========== 64x128 bf16 MFMA GEMM, BK=32, dbuf (R4/R7 sync discipline) ==========
// Tile 64x128, 4 waves (wr=w>>1 picks 32-row half, wc=w&1 picks 64-col half),
// each wave 32x64 = 2x4 frags of 16x16x32 -> acc[2][4]. Gate-interleave formula
// identical to the 128-tile version (4 n-frags per wave = 4 gates of one j).
// LDS 24 KB -> with grid 4 blocks/CU resident: 16 waves/CU of independent
// barrier groups overlap the per-block vmcnt drain (m114 mechanism).
// Staging: 12 chunks of 16 rows x 32 cols, 3 gl_lds per wave, 64B/row coalesced,
// linear LDS dest (rule #21). __syncthreads drains vmcnt per iter (proven R4/R7;
// deep rings double FETCH - measured R5/R6).
template <class ALd, class WLd, class Epi>
__global__ __launch_bounds__(256, 4) void gemm_t64(ALd al, WLd wl, Epi ep) {
    __shared__ ushort As[2 * 2048];   // [buf][row 64][32]
    __shared__ ushort Ws[2 * 4096];   // [buf][row 128][32]
    const int tid = threadIdx.x;
    const int lane = tid & 63;
    const int w = tid >> 6;
    const int wr = w >> 1, wc = w & 1;
    const int bn = blockIdx.x * 128 + al.bn0;
    const int bm = blockIdx.y * 64;
    const int grow = lane >> 2;          // 0..15 row within chunk
    const int gcol = (lane & 3) * 8;     // 0,8,16,24
    const int K = al.kdim(bn);
    const int nt = K >> 5;

    auto STAGE = [&](int ti, int buf) {
        const int k0 = ti * 32;
#pragma unroll
        for (int r = 0; r < 3; ++r) {
            const int i = w * 3 + r;     // 0..11, wave-uniform
            if (i < 4) {
                gl_lds16(al.addr(bn, bm + i * 16 + grow, k0 + gcol),
                         As + buf * 2048 + i * 512);
            } else {
                gl_lds16(wl.addr(bm, bn + (i - 4) * 16 + grow, k0 + gcol),
                         Ws + buf * 4096 + (i - 4) * 512);
            }
        }
    };

    f32x4 acc[2][4];
#pragma unroll
    for (int m = 0; m < 2; ++m)
#pragma unroll
        for (int n = 0; n < 4; ++n) acc[m][n] = (f32x4)0.0f;

    STAGE(0, 0);
    __syncthreads();

    const int frow = lane & 15, fk = (lane >> 4) * 8;
    const int foff = (wr * 32 + frow) * 32 + fk;
    const int goff = (wc * 64 + frow) * 32 + fk;

    for (int t = 0; t < nt; ++t) {
        if (t + 1 < nt) STAGE(t + 1, (t + 1) & 1);   // issue early; covered by reads+MFMA
        const ushort* asp = As + (t & 1) * 2048 + foff;
        const ushort* bsp = Ws + (t & 1) * 4096 + goff;
        bf16x8 af[2], bw[4];
#pragma unroll
        for (int m = 0; m < 2; ++m) af[m] = *(const bf16x8*)(asp + m * 512);
#pragma unroll
        for (int n = 0; n < 4; ++n) bw[n] = *(const bf16x8*)(bsp + n * 512);
#pragma unroll
        for (int m = 0; m < 2; ++m)
#pragma unroll
            for (int n = 0; n < 4; ++n)
                acc[m][n] = __builtin_amdgcn_mfma_f32_16x16x32_bf16(af[m], bw[n], acc[m][n], 0, 0, 0);
        __syncthreads();                 // drains vmcnt: next tile ready, buf reusable
    }
    ep(bm, bn, wr, wc, lane, acc);
}

// ================= loaders =================
struct ALdEnc {  // rows: dir*1024+b ; cols: [x_t(128) | h(1024)]
    const ushort* xe; const ushort* h; int bn0;
    __device__ int kdim(int) const { return 1152; }
    __device__ const ushort* addr(int, int row, int k) const {
        return (k < 128) ? xe + (size_t)row * 128 + k
                         : h + (size_t)row * 1024 + (k - 128);
    }
};
struct WLdEnc {  // [2][4096][1152] gate-interleaved, dir = bm>>10
    const ushort* W;
    __device__ const ushort* addr(int bm, int n, int k) const {
        return W + ((size_t)(bm >> 10) * 4096 + n) * 1152 + k;
    }
};
struct ALdDec {  // rows: b ; cols: [x_t | h | z]; bn>=5120 -> hid1prev (K=1024)
    const ushort* xd; const ushort* h; const ushort* z;
    const ushort* hid1prev; int bn0;
    __device__ int kdim(int bn) const {
        return bn < 4096 ? 1152 : (bn < 5120 ? 1280 : 1024);
    }
    __device__ const ushort* addr(int bn, int row, int k) const {
        if (bn >= 5120) return hid1prev + (size_t)row * 1024 + k;
        if (k < 128) return xd + (size_t)row * 128 + k;
        if (k < 1152) return h + (size_t)row * 1024 + (k - 128);
        return z + (size_t)row * 128 + (k - 1152);
    }
};
struct WLdDec {  // [4096][1152] gates | [1024][1280] W1 | [128][1024] W2pad
    const ushort* Wg4; const ushort* W1; const ushort* W2p;
    __device__ const ushort* addr(int, int n, int k) const {
        if (n < 4096) return Wg4 + (size_t)n * 1152 + k;
        if (n < 5120) return W1 + (size_t)(n - 4096) * 1280 + k;
        return W2p + (size_t)(n - 5120) * 1024 + k;
    }
};
struct ALdHid {  // hidden = [h_f | h_b]
    const ushort* hF; int bn0;
    __device__ int kdim(int) const { return 2048; }
    __device__ const ushort* addr(int, int row, int k) const {
        return hF + ((size_t)((k >> 10) << 10) + row) * 1024 + (k & 1023);
    }
};
struct ALdPlain {
    const ushort* A; int ld; int K; int bn0;
    __device__ int kdim(int) const { return K; }
    __device__ const ushort* addr(int, int row, int k) const { return A + (size_t)row * ld + k; }
};
struct WLdPlain {
    const ushort* W; int ld;
    __device__ const ushort* addr(int, int n, int k) const { return W + (size_t)n * ld + k; }
};

// ================= epilogues =================
struct EpiEnc {  // fused encoder LSTM cell; frag n = gate n (i,f,g,o); bf16 c
    const float* b_f; const float* b_b; const int* len; int t;
    ushort* c; const ushort* hc; ushort* hn;
    __device__ void operator()(int bm, int bn, int wr, int wc, int lane,
                               f32x4 (&acc)[2][4]) const {
        const int j = ((bn >> 6) + wc) * 16 + (lane & 15);
        const int rbase = bm + wr * 32 + ((lane >> 4) << 2);
#pragma unroll
        for (int m = 0; m < 2; ++m) {
#pragma unroll
            for (int r = 0; r < 4; ++r) {
                const int row = rbase + m * 16 + r;
                const int b = row & 1023;
                const float* bias = (row >> 10) ? b_b : b_f;
                const size_t o = (size_t)row * 1024 + j;
                if (t < len[b]) {
                    float gi = acc[m][0][r] + bias[j];
                    float gf = acc[m][1][r] + bias[1024 + j];
                    float gg = acc[m][2][r] + bias[2048 + j];
                    float go = acc[m][3][r] + bias[3072 + j];
                    float nc = sigf(gf) * bf2f(c[o]) + sigf(gi) * tanhfast(gg);
                    c[o] = f2bf(nc);
                    hn[o] = f2bf(sigf(go) * tanhfast(nc));
                } else {
                    hn[o] = hc[o];
                }
            }
        }
    }
};

struct EpiDec {
    const float *bi, *bo, *bfv, *bg, *b1, *b2;
    ushort* c; ushort* hn; ushort* hid1cur;
    const int* tokens; const int* len; int t;
    float* accs;
    __device__ void operator()(int bm, int bn, int wr, int wc, int lane,
                               f32x4 (&acc)[2][4]) const {
        const int rbase = bm + wr * 32 + ((lane >> 4) << 2);
        if (bn < 4096) {            // fused decoder LSTM cell (i,o,f,g); bf16 c
            const int j = ((bn >> 6) + wc) * 16 + (lane & 15);
#pragma unroll
            for (int m = 0; m < 2; ++m) {
#pragma unroll
                for (int r = 0; r < 4; ++r) {
                    const int b = rbase + m * 16 + r;
                    const size_t o = (size_t)b * 1024 + j;
                    float gi = sigf(acc[m][0][r] + bi[j]);
                    float go = sigf(acc[m][1][r] + bo[j]);
                    float gf = sigf(acc[m][2][r] + bfv[j]);
                    float gg = tanhfast(acc[m][3][r] + bg[j]);
                    float nc = gf * bf2f(c[o]) + gi * gg;
                    c[o] = f2bf(nc);
                    hn[o] = f2bf(go * tanhfast(nc));
                }
            }
        } else if (bn < 5120) {     // hid1 = relu(ah@W1^T + b1), bf16
            const int cb = (bn - 4096) + wc * 64;
#pragma unroll
            for (int m = 0; m < 2; ++m)
#pragma unroll
                for (int n = 0; n < 4; ++n) {
                    const int col = cb + n * 16 + (lane & 15);
#pragma unroll
                    for (int r = 0; r < 4; ++r)
                        hid1cur[(size_t)(rbase + m * 16 + r) * 1024 + col] =
                            f2bf(fmaxf(acc[m][n][r] + b1[col], 0.0f));
                }
        } else {                    // scores(t-1): CE/argmax, wave-parallel
            if (wc != 0) return;    // cols 64..127 are all >= V
            const int ts = t - 1;
            const int col0 = lane & 15;
            const bool v1ok = col0 < (V_ - 16);   // cols 16..20
            const float b2v0 = b2[col0];
            const float b2v1 = v1ok ? b2[16 + col0] : 0.0f;
            float ce_loc = 0.f, cor_loc = 0.f, msk_loc = 0.f;
#pragma unroll
            for (int m = 0; m < 2; ++m) {
#pragma unroll
                for (int r = 0; r < 4; ++r) {
                    const int b = rbase + m * 16 + r;
                    const int lb = len[b];
                    float v0 = acc[m][0][r] + b2v0;
                    float v1 = v1ok ? (acc[m][1][r] + b2v1) : -1e30f;
                    float mv; int mi;
                    if (v1 > v0) { mv = v1; mi = 16 + col0; } else { mv = v0; mi = col0; }
#pragma unroll
                    for (int s = 1; s < 16; s <<= 1) {
                        float ov = __shfl_xor(mv, s);
                        int oi = __shfl_xor(mi, s);
                        if (ov > mv || (ov == mv && oi < mi)) { mv = ov; mi = oi; }
                    }
                    float se = expf(v0 - mv) + (v1ok ? expf(v1 - mv) : 0.0f);
#pragma unroll
                    for (int s = 1; s < 16; s <<= 1) se += __shfl_xor(se, s);
                    float lse = mv + logf(se);
                    int tgt = (ts < lb) ? tokens[b * T_ + ts] : 0;
                    int srcl = (lane & 48) | (tgt & 15);
                    float sv0 = __shfl(v0, srcl);
                    float sv1 = __shfl(v1, srcl);
                    float stgt = (tgt < 16) ? sv0 : sv1;
                    if (ts <= lb && col0 == 0) {
                        ce_loc += lse - stgt;
                        cor_loc += (mi == tgt) ? 1.0f : 0.0f;
                        msk_loc += 1.0f;
                    }
                }
            }
            float ce = __shfl(ce_loc, 0) + __shfl(ce_loc, 16) + __shfl(ce_loc, 32) + __shfl(ce_loc, 48);
            float co = __shfl(cor_loc, 0) + __shfl(cor_loc, 16) + __shfl(cor_loc, 32) + __shfl(cor_loc, 48);
            float mk = __shfl(msk_loc, 0) + __shfl(msk_loc, 16) + __shfl(msk_loc, 32) + __shfl(msk_loc, 48);
            if (lane == 0) {
                atomicAdd(&accs[0], ce);
                atomicAdd(&accs[1], co);
                atomicAdd(&accs[2], mk);
            }
        }
    }
};

struct EpiStoreF32 {
    float* out; int ldc;
    __device__ void operator()(int bm, int bn, int wr, int wc, int lane,
                               f32x4 (&acc)[2][4]) const {
        const int rbase = bm + wr * 32 + ((lane >> 4) << 2);
        const int cbase = bn + wc * 64 + (lane & 15);
#pragma unroll
        for (int m = 0; m < 2; ++m)
#pragma unroll
            for (int n = 0; n < 4; ++n)
#pragma unroll
                for (int r = 0; r < 4; ++r)
                    out[(size_t)(rbase + m * 16 + r) * ldc + cbase + n * 16] = acc[m][n][r];
    }
};
struct EpiBiasBf16 {
    ushort* out; const float* bias;
    __device__ void operator()(int bm, int bn, int wr, int wc, int lane,
                               f32x4 (&acc)[2][4]) const {
        const int rbase = bm + wr * 32 + ((lane >> 4) << 2);
        const int cbase = bn + wc * 64 + (lane & 15);
#pragma unroll
        for (int m = 0; m < 2; ++m)
#pragma unroll
            for (int n = 0; n < 4; ++n) {
                const int col = cbase + n * 16;
#pragma unroll
                for (int r = 0; r < 4; ++r)
                    out[(size_t)(rbase + m * 16 + r) * 1024 + col] = f2bf(acc[m][n][r] + bias[col]);
            }
    }
};

// ================= packing / elementwise =================
__global__ void pack_cols(const float* __restrict__ src, int src_ld,
                          ushort* __restrict__ dst, int dst_ld, int dcol0,
                          int rows, int cols) {
    int i = blockIdx.x * 256 + threadIdx.x;
    int c4cnt = cols >> 2;
    if (i >= rows * c4cnt) return;
    int r = i / c4cnt, c4 = (i - r * c4cnt) * 4;
    float4 v = *(const float4*)(src + (size_t)r * src_ld + c4);
    ushort4 o = { f2bf(v.x), f2bf(v.y), f2bf(v.z), f2bf(v.w) };
    *(ushort4*)(dst + (size_t)r * dst_ld + dcol0 + c4) = o;
}

__global__ void pack_gates_enc(const float* __restrict__ Wih_f, const float* __restrict__ Whh_f,
                               const float* __restrict__ Wih_b, const float* __restrict__ Whh_b,
                               ushort* __restrict__ dst) {
    int i = blockIdx.x * 256 + threadIdx.x;   // 2*4096*288
    if (i >= 2 * 4096 * 288) return;
    int c4 = (i % 288) * 4;
    int p = (i / 288) & 4095;
    int dir = i / (288 * 4096);
    int j = ((p >> 6) << 4) + (p & 15);
    int g = (p >> 4) & 3;
    int srow = g * 1024 + j;
    float4 v;
    if (c4 < 128) {
        const float* s = dir ? Wih_b : Wih_f;
        v = *(const float4*)(s + (size_t)srow * 128 + c4);
    } else {
        const float* s = dir ? Whh_b : Whh_f;
        v = *(const float4*)(s + (size_t)srow * 1024 + (c4 - 128));
    }
    ushort4 o = { f2bf(v.x), f2bf(v.y), f2bf(v.z), f2bf(v.w) };
    *(ushort4*)(dst + ((size_t)dir * 4096 + p) * 1152 + c4) = o;
}

__global__ void pack_gates_dec(const float* __restrict__ Wi, const float* __restrict__ Wo,
                               const float* __restrict__ Wf, const float* __restrict__ Wg,
                               ushort* __restrict__ dst) {
    int i = blockIdx.x * 256 + threadIdx.x;   // 4096*288
    if (i >= 4096 * 288) return;
    int c4 = (i % 288) * 4;
    int p = i / 288;
    int j = ((p >> 6) << 4) + (p & 15);
    int g = (p >> 4) & 3;
    const float* s = (g == 0) ? Wi : (g == 1) ? Wo : (g == 2) ? Wf : Wg;
    float4 v = *(const float4*)(s + (size_t)j * 1152 + c4);
    ushort4 o = { f2bf(v.x), f2bf(v.y), f2bf(v.z), f2bf(v.w) };
    *(ushort4*)(dst + (size_t)p * 1152 + c4) = o;
}

__global__ void pack_w2(const float* __restrict__ W2, ushort* __restrict__ dst) {
    int i = blockIdx.x * 256 + threadIdx.x;   // 128*256
    if (i >= 128 * 256) return;
    int r = i >> 8, c4 = (i & 255) * 4;
    ushort4 o = { 0, 0, 0, 0 };
    if (r < V_) {
        float4 v = *(const float4*)(W2 + (size_t)r * 1024 + c4);
        o = ushort4{ f2bf(v.x), f2bf(v.y), f2bf(v.z), f2bf(v.w) };
    }
    *(ushort4*)(dst + (size_t)r * 1024 + c4) = o;
}

__global__ void pack_xenc(const float* __restrict__ xenc, const int* __restrict__ len,
                          ushort* __restrict__ xe) {
    int i = blockIdx.x * 256 + threadIdx.x;   // 15*2048*32
    if (i >= 15 * 2048 * 32) return;
    int c4 = (i & 31) * 4;
    int r = (i >> 5) & 2047;
    int t = i >> 16;
    int dir = r >> 10, b = r & 1023;
    int tt = t;
    if (dir) {
        int ri = len[b] - 1 - t;
        tt = ri < 0 ? 0 : (ri > T_ - 1 ? T_ - 1 : ri);
    }
    float4 v = *(const float4*)(xenc + ((size_t)b * T_ + tt) * 128 + c4);
    ushort4 o = { f2bf(v.x), f2bf(v.y), f2bf(v.z), f2bf(v.w) };
    *(ushort4*)(xe + ((size_t)t * 2048 + r) * 128 + c4) = o;
}

__global__ void pack_xdec(const float* __restrict__ emb, const int* __restrict__ tokens,
                          ushort* __restrict__ xd) {
    int i = blockIdx.x * 256 + threadIdx.x;   // 15*1024*32
    if (i >= 15 * 1024 * 32) return;
    int c4 = (i & 31) * 4;
    int b = (i >> 5) & 1023;
    int t = i >> 15;
    ushort4 o = { 0, 0, 0, 0 };
    if (t > 0) {
        int tok = tokens[(size_t)b * T_ + (t - 1)];
        float4 v = *(const float4*)(emb + (size_t)tok * 128 + c4);
        o = ushort4{ f2bf(v.x), f2bf(v.y), f2bf(v.z), f2bf(v.w) };
    }
    *(ushort4*)(xd + ((size_t)t * 1024 + b) * 128 + c4) = o;
}

__global__ void init_zero(ushort* cenc, ushort* cdec, ushort* hA, float* accs) {
    int i = blockIdx.x * 256 + threadIdx.x;
    if (i < 2 * 1024 * 1024) { cenc[i] = 0; hA[i] = 0; }
    if (i < 1024 * 1024) cdec[i] = 0;
    if (i < 8) accs[i] = 0.0f;
}

__global__ void latent_ew(const float* __restrict__ ml, const float* __restrict__ bmv,
                          const float* __restrict__ blv, const float* __restrict__ eps,
                          ushort* __restrict__ zp, float* __restrict__ klacc) {
    int idx = blockIdx.x * 256 + threadIdx.x;
    int b = idx >> 7, l = idx & (L_ - 1);
    float mean = ml[(size_t)b * 256 + l] + bmv[l];
    float logv = ml[(size_t)b * 256 + L_ + l] + blv[l];
    zp[idx] = f2bf(eps[idx] * expf(0.5f * logv) + mean);
    float part = 1.0f + logv - mean * mean - expf(logv);
    for (int off = 32; off; off >>= 1) part += __shfl_down(part, off);
    __shared__ float s[4];
    int lane = threadIdx.x & 63, wv = threadIdx.x >> 6;
    if (lane == 0) s[wv] = part;
    __syncthreads();
    if (threadIdx.x == 0) atomicAdd(klacc, s[0] + s[1] + s[2] + s[3]);
}

__global__ void finalize_k(const float* accs, float* out) {
    if (threadIdx.x == 0 && blockIdx.x == 0) {
        float kl = -0.5f * accs[3] / (float)B_;
        float amino = accs[0] / (float)B_;
        out[0] = amino + 0.1f * kl;
        out[1] = amino;
        out[2] = kl;
        out[3] = accs[1] / accs[2];
    }
}

// ================= host =================
extern "C" void kernel_launch(void* const* d_in, const int* in_sizes, int n_in,
                              void* d_out, int out_size, void* d_ws, size_t ws_size,
                              hipStream_t stream) {
    (void)in_sizes; (void)n_in; (void)out_size; (void)ws_size;
    const float* x_enc  = (const float*)d_in[0];
    const int*   tokens = (const int*)d_in[1];
    const int*   lengths= (const int*)d_in[2];
    const float* eps    = (const float*)d_in[3];
    const float* emb    = (const float*)d_in[4];
    const float* Wih_f  = (const float*)d_in[5];
    const float* Whh_f  = (const float*)d_in[6];
    const float* b_f    = (const float*)d_in[7];
    const float* Wih_b  = (const float*)d_in[8];
    const float* Whh_b  = (const float*)d_in[9];
    const float* b_b    = (const float*)d_in[10];
    const float* Wm     = (const float*)d_in[11];
    const float* bm     = (const float*)d_in[12];
    const float* Wl     = (const float*)d_in[13];
    const float* bl     = (const float*)d_in[14];
    const float* Wz     = (const float*)d_in[15];
    const float* bz     = (const float*)d_in[16];
    const float* Wi     = (const float*)d_in[17];
    const float* bi     = (const float*)d_in[18];
    const float* Wo     = (const float*)d_in[19];
    const float* bo     = (const float*)d_in[20];
    const float* Wfm    = (const float*)d_in[21];
    const float* bf     = (const float*)d_in[22];
    const float* Wg     = (const float*)d_in[23];
    const float* bg     = (const float*)d_in[24];
    const float* W1     = (const float*)d_in[25];
    const float* b1     = (const float*)d_in[26];
    const float* W2     = (const float*)d_in[27];
    const float* b2     = (const float*)d_in[28];

    float*  ml   = (float*)d_ws;                    // 256K f32
    float*  accs = ml + 1024 * 256;                 // 8 (+pad 64)
    ushort* cenc = (ushort*)(accs + 64);            // 2M bf16
    ushort* cdec = cenc + 2 * 1024 * 1024;          // 1M bf16
    ushort* hA   = cdec + 1024 * 1024;              // 2M
    ushort* hB   = hA + 2 * 1024 * 1024;
    ushort* hdA  = hB + 2 * 1024 * 1024;            // 1M
    ushort* hdB  = hdA + 1024 * 1024;
    ushort* h1A  = hdB + 1024 * 1024;               // 1M
    ushort* h1B  = h1A + 1024 * 1024;
    ushort* zp   = h1B + 1024 * 1024;               // 128K
    ushort* xe   = zp + 1024 * 128;                 // 15*2048*128
    ushort* xd   = xe + 15 * 2048 * 128;            // 15*1024*128
    ushort* Wenc = xd + 15 * 1024 * 128;            // 2*4096*1152
    ushort* Wdec = Wenc + 2 * 4096 * 1152;          // 4096*1152
    ushort* W1p  = Wdec + 4096 * 1152;              // 1024*1280
    ushort* Wml  = W1p + 1024 * 1280;               // 256*2048
    ushort* Wzp  = Wml + 256 * 2048;                // 1024*128
    ushort* W2p  = Wzp + 1024 * 128;                // 128*1024

    init_zero<<<8192, 256, 0, stream>>>(cenc, cdec, hA, accs);
    pack_gates_enc<<<9216, 256, 0, stream>>>(Wih_f, Whh_f, Wih_b, Whh_b, Wenc);
    pack_gates_dec<<<4608, 256, 0, stream>>>(Wi, Wo, Wfm, Wg, Wdec);
    pack_cols<<<1280, 256, 0, stream>>>(W1, 1280, W1p, 1280, 0, 1024, 1280);
    pack_cols<<<256, 256, 0, stream>>>(Wm, 2048, Wml, 2048, 0, L_, 2048);
    pack_cols<<<256, 256, 0, stream>>>(Wl, 2048, Wml + L_ * 2048, 2048, 0, L_, 2048);
    pack_cols<<<128, 256, 0, stream>>>(Wz, L_, Wzp, L_, 0, H_, L_);
    pack_w2<<<128, 256, 0, stream>>>(W2, W2p);
    pack_xenc<<<3840, 256, 0, stream>>>(x_enc, lengths, xe);
    pack_xdec<<<1920, 256, 0, stream>>>(emb, tokens, xd);

    // ---- encoder: grid (32, 32) = 1024 blocks = 4/CU ----
    {
        const ushort* hc = hA; ushort* hn = hB;
        for (int t = 0; t < T_; ++t) {
            gemm_t64<<<dim3(32, 32), 256, 0, stream>>>(
                ALdEnc{ xe + (size_t)t * 2048 * 128, hc, 0 }, WLdEnc{ Wenc },
                EpiEnc{ b_f, b_b, lengths, t, cenc, hc, hn });
            const ushort* tmp = hn; hn = (ushort*)hc; hc = tmp;
        }
        gemm_t64<<<dim3(2, 16), 256, 0, stream>>>(
            ALdHid{ hc, 0 }, WLdPlain{ Wml, 2048 }, EpiStoreF32{ ml, 256 });
    }
    latent_ew<<<512, 256, 0, stream>>>(ml, bm, bl, eps, zp, &accs[3]);
    gemm_t64<<<dim3(8, 16), 256, 0, stream>>>(
        ALdPlain{ zp, 128, 128, 0 }, WLdPlain{ Wzp, 128 }, EpiBiasBf16{ hdA, bz });

    // ---- decoder: grid (41, 16) = 656 blocks; scores(t-1) fused ----
    {
        const ushort* dc = hdA; ushort* dn = hdB;
        for (int t = 0; t < T_; ++t) {
            ushort* h1c = (t & 1) ? h1B : h1A;
            const ushort* h1p = (t & 1) ? h1A : h1B;
            dim3 grid(t == 0 ? 40 : 41, 16);
            gemm_t64<<<grid, 256, 0, stream>>>(
                ALdDec{ xd + (size_t)t * 1024 * 128, dc, zp, h1p, 0 },
                WLdDec{ Wdec, W1p, W2p },
                EpiDec{ bi, bo, bf, bg, b1, b2, cdec, dn, h1c, tokens, lengths, t, accs });
            const ushort* tmp = dn; dn = (ushort*)dc; dc = tmp;
        }
        const ushort* h1p14 = ((T_ - 1) & 1) ? h1B : h1A;  // hid1 written at t=14
        gemm_t64<<<dim3(1, 16), 256, 0, stream>>>(
            ALdDec{ xd, dc, zp, h1p14, 5120 },
            WLdDec{ Wdec, W1p, W2p },
            EpiDec{ bi, bo, bf, bg, b1, b2, cdec, hdB, h1B, tokens, lengths, T_, accs });
    }

    finalize_k<<<1, 64, 0, stream>>>(accs, (float*)d_out);
}

// Round 9
// 1165.918 us; speedup vs baseline: 1.9089x; 1.0740x over previous
//
#include <hip/hip_runtime.h>
#include <math.h>

#define B_ 1024
#define T_ 15
#define E_ 128
#define H_ 1024
#define L_ 128
#define V_ 21

typedef __attribute__((ext_vector_type(8))) short bf16x8;
typedef __attribute__((ext_vector_type(4))) float f32x4;

// overflow-safe fast sigmoid / tanh (v_exp_f32 path)
__device__ __forceinline__ float sigf(float x) { return 1.0f / (1.0f + __expf(-x)); }
__device__ __forceinline__ float tanhfast(float x) {
    float t = __expf(-2.0f * fabsf(x));          // in (0,1], never overflows
    float r = (1.0f - t) / (1.0f + t);
    return copysignf(r, x);
}

__device__ __forceinline__ ushort f2bf(float f) {
    unsigned u = __float_as_uint(f);
    u += 0x7fffu + ((u >> 16) & 1u);
    return (ushort)(u >> 16);
}
__device__ __forceinline__ float bf2f(ushort u) {
    return __uint_as_float((unsigned)u << 16);
}

__device__ __forceinline__ void gl_lds16(const ushort* g, ushort* l) {
    __builtin_amdgcn_global_load_lds(
        (const __attribute__((address_space(1))) void*)g,
        (__attribute__((address_space(3))) void*)l, 16, 0, 0);
}

// ========== 64x128 bf16 MFMA GEMM, BK=32, dbuf, hoisted staging pointers ==========
// R8 geometry: tile 64x128, 4 waves (wr|wc), wave 32x64 = acc[2][4] of 16x16x32,
// LDS 24 KB, 4 blocks/CU. New in R9: per-wave staging pointers are computed ONCE
// and advanced +32 elems/iter; loaders expose reloadAt(k) for their (tile-aligned)
// region boundaries (x|h at 128, h|z at 1152, hid at 1024). Cuts ~100 VALU/iter
// of address math (VALUBusy 31% -> ~14% predicted).
template <class ALd, class WLd, class Epi>
__global__ __launch_bounds__(256, 4) void gemm_t64(ALd al, WLd wl, Epi ep) {
    __shared__ ushort As[2 * 2048];   // [buf][row 64][32]
    __shared__ ushort Ws[2 * 4096];   // [buf][row 128][32]
    const int tid = threadIdx.x;
    const int lane = tid & 63;
    const int w = tid >> 6;
    const int wr = w >> 1, wc = w & 1;
    const int bn = blockIdx.x * 128 + al.bn0;
    const int bm = blockIdx.y * 64;
    const int grow = lane >> 2;          // row within 16-row chunk
    const int gcol = (lane & 3) * 8;     // 0,8,16,24
    const int K = al.kdim(bn);
    const int nt = K >> 5;

    // wave w stages chunks i = w*3 + r (i<4: A rows i*16.., else W rows (i-4)*16..)
    const ushort* gp[3];
    ushort* ld0[3];
    int lstride[3];
    bool isA[3];
#pragma unroll
    for (int r = 0; r < 3; ++r) {
        const int i = w * 3 + r;
        isA[r] = (i < 4);
        ld0[r] = isA[r] ? (As + i * 512) : (Ws + (i - 4) * 512);
        lstride[r] = isA[r] ? 2048 : 4096;
        gp[r] = isA[r] ? al.addr(bn, bm + i * 16 + grow, gcol)
                       : wl.addr(bm, bn + (i - 4) * 16 + grow, gcol);
    }

    auto STAGE = [&](int k0, int buf) {
#pragma unroll
        for (int r = 0; r < 3; ++r) {
            if (isA[r]) {
                if (al.reloadAt(k0))
                    gp[r] = al.addr(bn, bm + (w * 3 + r) * 16 + grow, k0 + gcol);
            } else {
                if (wl.reloadAt(k0))
                    gp[r] = wl.addr(bm, bn + (w * 3 + r - 4) * 16 + grow, k0 + gcol);
            }
            gl_lds16(gp[r], ld0[r] + (buf ? lstride[r] : 0));
            gp[r] += 32;
        }
    };

    f32x4 acc[2][4];
#pragma unroll
    for (int m = 0; m < 2; ++m)
#pragma unroll
        for (int n = 0; n < 4; ++n) acc[m][n] = (f32x4)0.0f;

    STAGE(0, 0);
    __syncthreads();

    const int frow = lane & 15, fk = (lane >> 4) * 8;
    const int foff = (wr * 32 + frow) * 32 + fk;
    const int goff = (wc * 64 + frow) * 32 + fk;

    for (int t = 0; t < nt; ++t) {
        if (t + 1 < nt) STAGE((t + 1) * 32, (t + 1) & 1);   // covered by reads+MFMA
        const ushort* asp = As + (t & 1) * 2048 + foff;
        const ushort* bsp = Ws + (t & 1) * 4096 + goff;
        bf16x8 af[2], bw[4];
#pragma unroll
        for (int m = 0; m < 2; ++m) af[m] = *(const bf16x8*)(asp + m * 512);
#pragma unroll
        for (int n = 0; n < 4; ++n) bw[n] = *(const bf16x8*)(bsp + n * 512);
#pragma unroll
        for (int m = 0; m < 2; ++m)
#pragma unroll
            for (int n = 0; n < 4; ++n)
                acc[m][n] = __builtin_amdgcn_mfma_f32_16x16x32_bf16(af[m], bw[n], acc[m][n], 0, 0, 0);
        __syncthreads();                 // drains vmcnt: next tile ready, buf reusable
    }
    ep(bm, bn, wr, wc, lane, acc);
}

// ================= loaders =================
struct ALdEnc {  // rows: dir*1024+b ; cols: [x_t(128) | h(1024)]
    const ushort* xe; const ushort* h; int bn0;
    __device__ int kdim(int) const { return 1152; }
    __device__ bool reloadAt(int k) const { return k == 128; }
    __device__ const ushort* addr(int, int row, int k) const {
        return (k < 128) ? xe + (size_t)row * 128 + k
                         : h + (size_t)row * 1024 + (k - 128);
    }
};
struct WLdEnc {  // [2][4096][1152] gate-interleaved, dir = bm>>10
    const ushort* W;
    __device__ bool reloadAt(int) const { return false; }
    __device__ const ushort* addr(int bm, int n, int k) const {
        return W + ((size_t)(bm >> 10) * 4096 + n) * 1152 + k;
    }
};
struct ALdDec {  // rows: b ; cols: [x_t | h | z]; bn>=5120 -> hid1prev (K=1024)
    const ushort* xd; const ushort* h; const ushort* z;
    const ushort* hid1prev; int bn0;
    __device__ int kdim(int bn) const {
        return bn < 4096 ? 1152 : (bn < 5120 ? 1280 : 1024);
    }
    __device__ bool reloadAt(int k) const { return k == 128 || k == 1152; }
    __device__ const ushort* addr(int bn, int row, int k) const {
        if (bn >= 5120) return hid1prev + (size_t)row * 1024 + k;
        if (k < 128) return xd + (size_t)row * 128 + k;
        if (k < 1152) return h + (size_t)row * 1024 + (k - 128);
        return z + (size_t)row * 128 + (k - 1152);
    }
};
struct WLdDec {  // [4096][1152] gates | [1024][1280] W1 | [128][1024] W2pad
    const ushort* Wg4; const ushort* W1; const ushort* W2p;
    __device__ bool reloadAt(int) const { return false; }
    __device__ const ushort* addr(int, int n, int k) const {
        if (n < 4096) return Wg4 + (size_t)n * 1152 + k;
        if (n < 5120) return W1 + (size_t)(n - 4096) * 1280 + k;
        return W2p + (size_t)(n - 5120) * 1024 + k;
    }
};
struct ALdHid {  // hidden = [h_f | h_b]
    const ushort* hF; int bn0;
    __device__ int kdim(int) const { return 2048; }
    __device__ bool reloadAt(int k) const { return k == 1024; }
    __device__ const ushort* addr(int, int row, int k) const {
        return hF + ((size_t)((k >> 10) << 10) + row) * 1024 + (k & 1023);
    }
};
struct ALdPlain {
    const ushort* A; int ld; int K; int bn0;
    __device__ int kdim(int) const { return K; }
    __device__ bool reloadAt(int) const { return false; }
    __device__ const ushort* addr(int, int row, int k) const { return A + (size_t)row * ld + k; }
};
struct WLdPlain {
    const ushort* W; int ld;
    __device__ bool reloadAt(int) const { return false; }
    __device__ const ushort* addr(int, int n, int k) const { return W + (size_t)n * ld + k; }
};

// ================= epilogues =================
struct EpiEnc {  // fused encoder LSTM cell; frag n = gate n (i,f,g,o); bf16 c
    const float* b_f; const float* b_b; const int* len; int t;
    ushort* c; const ushort* hc; ushort* hn;
    __device__ void operator()(int bm, int bn, int wr, int wc, int lane,
                               f32x4 (&acc)[2][4]) const {
        const int j = ((bn >> 6) + wc) * 16 + (lane & 15);
        const int rbase = bm + wr * 32 + ((lane >> 4) << 2);
#pragma unroll
        for (int m = 0; m < 2; ++m) {
#pragma unroll
            for (int r = 0; r < 4; ++r) {
                const int row = rbase + m * 16 + r;
                const int b = row & 1023;
                const float* bias = (row >> 10) ? b_b : b_f;
                const size_t o = (size_t)row * 1024 + j;
                if (t < len[b]) {
                    float gi = acc[m][0][r] + bias[j];
                    float gf = acc[m][1][r] + bias[1024 + j];
                    float gg = acc[m][2][r] + bias[2048 + j];
                    float go = acc[m][3][r] + bias[3072 + j];
                    float nc = sigf(gf) * bf2f(c[o]) + sigf(gi) * tanhfast(gg);
                    c[o] = f2bf(nc);
                    hn[o] = f2bf(sigf(go) * tanhfast(nc));
                } else {
                    hn[o] = hc[o];
                }
            }
        }
    }
};

struct EpiDec {
    const float *bi, *bo, *bfv, *bg, *b1, *b2;
    ushort* c; ushort* hn; ushort* hid1cur;
    const int* tokens; const int* len; int t;
    float* accs;
    __device__ void operator()(int bm, int bn, int wr, int wc, int lane,
                               f32x4 (&acc)[2][4]) const {
        const int rbase = bm + wr * 32 + ((lane >> 4) << 2);
        if (bn < 4096) {            // fused decoder LSTM cell (i,o,f,g); bf16 c
            const int j = ((bn >> 6) + wc) * 16 + (lane & 15);
#pragma unroll
            for (int m = 0; m < 2; ++m) {
#pragma unroll
                for (int r = 0; r < 4; ++r) {
                    const int b = rbase + m * 16 + r;
                    const size_t o = (size_t)b * 1024 + j;
                    float gi = sigf(acc[m][0][r] + bi[j]);
                    float go = sigf(acc[m][1][r] + bo[j]);
                    float gf = sigf(acc[m][2][r] + bfv[j]);
                    float gg = tanhfast(acc[m][3][r] + bg[j]);
                    float nc = gf * bf2f(c[o]) + gi * gg;
                    c[o] = f2bf(nc);
                    hn[o] = f2bf(go * tanhfast(nc));
                }
            }
        } else if (bn < 5120) {     // hid1 = relu(ah@W1^T + b1), bf16
            const int cb = (bn - 4096) + wc * 64;
#pragma unroll
            for (int m = 0; m < 2; ++m)
#pragma unroll
                for (int n = 0; n < 4; ++n) {
                    const int col = cb + n * 16 + (lane & 15);
#pragma unroll
                    for (int r = 0; r < 4; ++r)
                        hid1cur[(size_t)(rbase + m * 16 + r) * 1024 + col] =
                            f2bf(fmaxf(acc[m][n][r] + b1[col], 0.0f));
                }
        } else {                    // scores(t-1): CE/argmax, wave-parallel
            if (wc != 0) return;    // cols 64..127 are all >= V
            const int ts = t - 1;
            const int col0 = lane & 15;
            const bool v1ok = col0 < (V_ - 16);   // cols 16..20
            const float b2v0 = b2[col0];
            const float b2v1 = v1ok ? b2[16 + col0] : 0.0f;
            float ce_loc = 0.f, cor_loc = 0.f, msk_loc = 0.f;
#pragma unroll
            for (int m = 0; m < 2; ++m) {
#pragma unroll
                for (int r = 0; r < 4; ++r) {
                    const int b = rbase + m * 16 + r;
                    const int lb = len[b];
                    float v0 = acc[m][0][r] + b2v0;
                    float v1 = v1ok ? (acc[m][1][r] + b2v1) : -1e30f;
                    float mv; int mi;
                    if (v1 > v0) { mv = v1; mi = 16 + col0; } else { mv = v0; mi = col0; }
#pragma unroll
                    for (int s = 1; s < 16; s <<= 1) {
                        float ov = __shfl_xor(mv, s);
                        int oi = __shfl_xor(mi, s);
                        if (ov > mv || (ov == mv && oi < mi)) { mv = ov; mi = oi; }
                    }
                    float se = expf(v0 - mv) + (v1ok ? expf(v1 - mv) : 0.0f);
#pragma unroll
                    for (int s = 1; s < 16; s <<= 1) se += __shfl_xor(se, s);
                    float lse = mv + logf(se);
                    int tgt = (ts < lb) ? tokens[b * T_ + ts] : 0;
                    int srcl = (lane & 48) | (tgt & 15);
                    float sv0 = __shfl(v0, srcl);
                    float sv1 = __shfl(v1, srcl);
                    float stgt = (tgt < 16) ? sv0 : sv1;
                    if (ts <= lb && col0 == 0) {
                        ce_loc += lse - stgt;
                        cor_loc += (mi == tgt) ? 1.0f : 0.0f;
                        msk_loc += 1.0f;
                    }
                }
            }
            float ce = __shfl(ce_loc, 0) + __shfl(ce_loc, 16) + __shfl(ce_loc, 32) + __shfl(ce_loc, 48);
            float co = __shfl(cor_loc, 0) + __shfl(cor_loc, 16) + __shfl(cor_loc, 32) + __shfl(cor_loc, 48);
            float mk = __shfl(msk_loc, 0) + __shfl(msk_loc, 16) + __shfl(msk_loc, 32) + __shfl(msk_loc, 48);
            if (lane == 0) {
                atomicAdd(&accs[0], ce);
                atomicAdd(&accs[1], co);
                atomicAdd(&accs[2], mk);
            }
        }
    }
};

struct EpiStoreF32 {
    float* out; int ldc;
    __device__ void operator()(int bm, int bn, int wr, int wc, int lane,
                               f32x4 (&acc)[2][4]) const {
        const int rbase = bm + wr * 32 + ((lane >> 4) << 2);
        const int cbase = bn + wc * 64 + (lane & 15);
#pragma unroll
        for (int m = 0; m < 2; ++m)
#pragma unroll
            for (int n = 0; n < 4; ++n)
#pragma unroll
                for (int r = 0; r < 4; ++r)
                    out[(size_t)(rbase + m * 16 + r) * ldc + cbase + n * 16] = acc[m][n][r];
    }
};
struct EpiBiasBf16 {
    ushort* out; const float* bias;
    __device__ void operator()(int bm, int bn, int wr, int wc, int lane,
                               f32x4 (&acc)[2][4]) const {
        const int rbase = bm + wr * 32 + ((lane >> 4) << 2);
        const int cbase = bn + wc * 64 + (lane & 15);
#pragma unroll
        for (int m = 0; m < 2; ++m)
#pragma unroll
            for (int n = 0; n < 4; ++n) {
                const int col = cbase + n * 16;
#pragma unroll
                for (int r = 0; r < 4; ++r)
                    out[(size_t)(rbase + m * 16 + r) * 1024 + col] = f2bf(acc[m][n][r] + bias[col]);
            }
    }
};

// ================= packing / elementwise =================
__global__ void pack_cols(const float* __restrict__ src, int src_ld,
                          ushort* __restrict__ dst, int dst_ld, int dcol0,
                          int rows, int cols) {
    int i = blockIdx.x * 256 + threadIdx.x;
    int c4cnt = cols >> 2;
    if (i >= rows * c4cnt) return;
    int r = i / c4cnt, c4 = (i - r * c4cnt) * 4;
    float4 v = *(const float4*)(src + (size_t)r * src_ld + c4);
    ushort4 o = { f2bf(v.x), f2bf(v.y), f2bf(v.z), f2bf(v.w) };
    *(ushort4*)(dst + (size_t)r * dst_ld + dcol0 + c4) = o;
}

__global__ void pack_gates_enc(const float* __restrict__ Wih_f, const float* __restrict__ Whh_f,
                               const float* __restrict__ Wih_b, const float* __restrict__ Whh_b,
                               ushort* __restrict__ dst) {
    int i = blockIdx.x * 256 + threadIdx.x;   // 2*4096*288
    if (i >= 2 * 4096 * 288) return;
    int c4 = (i % 288) * 4;
    int p = (i / 288) & 4095;
    int dir = i / (288 * 4096);
    int j = ((p >> 6) << 4) + (p & 15);
    int g = (p >> 4) & 3;
    int srow = g * 1024 + j;
    float4 v;
    if (c4 < 128) {
        const float* s = dir ? Wih_b : Wih_f;
        v = *(const float4*)(s + (size_t)srow * 128 + c4);
    } else {
        const float* s = dir ? Whh_b : Whh_f;
        v = *(const float4*)(s + (size_t)srow * 1024 + (c4 - 128));
    }
    ushort4 o = { f2bf(v.x), f2bf(v.y), f2bf(v.z), f2bf(v.w) };
    *(ushort4*)(dst + ((size_t)dir * 4096 + p) * 1152 + c4) = o;
}

__global__ void pack_gates_dec(const float* __restrict__ Wi, const float* __restrict__ Wo,
                               const float* __restrict__ Wf, const float* __restrict__ Wg,
                               ushort* __restrict__ dst) {
    int i = blockIdx.x * 256 + threadIdx.x;   // 4096*288
    if (i >= 4096 * 288) return;
    int c4 = (i % 288) * 4;
    int p = i / 288;
    int j = ((p >> 6) << 4) + (p & 15);
    int g = (p >> 4) & 3;
    const float* s = (g == 0) ? Wi : (g == 1) ? Wo : (g == 2) ? Wf : Wg;
    float4 v = *(const float4*)(s + (size_t)j * 1152 + c4);
    ushort4 o = { f2bf(v.x), f2bf(v.y), f2bf(v.z), f2bf(v.w) };
    *(ushort4*)(dst + (size_t)p * 1152 + c4) = o;
}

__global__ void pack_w2(const float* __restrict__ W2, ushort* __restrict__ dst) {
    int i = blockIdx.x * 256 + threadIdx.x;   // 128*256
    if (i >= 128 * 256) return;
    int r = i >> 8, c4 = (i & 255) * 4;
    ushort4 o = { 0, 0, 0, 0 };
    if (r < V_) {
        float4 v = *(const float4*)(W2 + (size_t)r * 1024 + c4);
        o = ushort4{ f2bf(v.x), f2bf(v.y), f2bf(v.z), f2bf(v.w) };
    }
    *(ushort4*)(dst + (size_t)r * 1024 + c4) = o;
}

__global__ void pack_xenc(const float* __restrict__ xenc, const int* __restrict__ len,
                          ushort* __restrict__ xe) {
    int i = blockIdx.x * 256 + threadIdx.x;   // 15*2048*32
    if (i >= 15 * 2048 * 32) return;
    int c4 = (i & 31) * 4;
    int r = (i >> 5) & 2047;
    int t = i >> 16;
    int dir = r >> 10, b = r & 1023;
    int tt = t;
    if (dir) {
        int ri = len[b] - 1 - t;
        tt = ri < 0 ? 0 : (ri > T_ - 1 ? T_ - 1 : ri);
    }
    float4 v = *(const float4*)(xenc + ((size_t)b * T_ + tt) * 128 + c4);
    ushort4 o = { f2bf(v.x), f2bf(v.y), f2bf(v.z), f2bf(v.w) };
    *(ushort4*)(xe + ((size_t)t * 2048 + r) * 128 + c4) = o;
}

__global__ void pack_xdec(const float* __restrict__ emb, const int* __restrict__ tokens,
                          ushort* __restrict__ xd) {
    int i = blockIdx.x * 256 + threadIdx.x;   // 15*1024*32
    if (i >= 15 * 1024 * 32) return;
    int c4 = (i & 31) * 4;
    int b = (i >> 5) & 1023;
    int t = i >> 15;
    ushort4 o = { 0, 0, 0, 0 };
    if (t > 0) {
        int tok = tokens[(size_t)b * T_ + (t - 1)];
        float4 v = *(const float4*)(emb + (size_t)tok * 128 + c4);
        o = ushort4{ f2bf(v.x), f2bf(v.y), f2bf(v.z), f2bf(v.w) };
    }
    *(ushort4*)(xd + ((size_t)t * 1024 + b) * 128 + c4) = o;
}

__global__ void init_zero(ushort* cenc, ushort* cdec, ushort* hA, float* accs) {
    int i = blockIdx.x * 256 + threadIdx.x;
    if (i < 2 * 1024 * 1024) { cenc[i] = 0; hA[i] = 0; }
    if (i < 1024 * 1024) cdec[i] = 0;
    if (i < 8) accs[i] = 0.0f;
}

__global__ void latent_ew(const float* __restrict__ ml, const float* __restrict__ bmv,
                          const float* __restrict__ blv, const float* __restrict__ eps,
                          ushort* __restrict__ zp, float* __restrict__ klacc) {
    int idx = blockIdx.x * 256 + threadIdx.x;
    int b = idx >> 7, l = idx & (L_ - 1);
    float mean = ml[(size_t)b * 256 + l] + bmv[l];
    float logv = ml[(size_t)b * 256 + L_ + l] + blv[l];
    zp[idx] = f2bf(eps[idx] * expf(0.5f * logv) + mean);
    float part = 1.0f + logv - mean * mean - expf(logv);
    for (int off = 32; off; off >>= 1) part += __shfl_down(part, off);
    __shared__ float s[4];
    int lane = threadIdx.x & 63, wv = threadIdx.x >> 6;
    if (lane == 0) s[wv] = part;
    __syncthreads();
    if (threadIdx.x == 0) atomicAdd(klacc, s[0] + s[1] + s[2] + s[3]);
}

__global__ void finalize_k(const float* accs, float* out) {
    if (threadIdx.x == 0 && blockIdx.x == 0) {
        float kl = -0.5f * accs[3] / (float)B_;
        float amino = accs[0] / (float)B_;
        out[0] = amino + 0.1f * kl;
        out[1] = amino;
        out[2] = kl;
        out[3] = accs[1] / accs[2];
    }
}

// ================= host =================
extern "C" void kernel_launch(void* const* d_in, const int* in_sizes, int n_in,
                              void* d_out, int out_size, void* d_ws, size_t ws_size,
                              hipStream_t stream) {
    (void)in_sizes; (void)n_in; (void)out_size; (void)ws_size;
    const float* x_enc  = (const float*)d_in[0];
    const int*   tokens = (const int*)d_in[1];
    const int*   lengths= (const int*)d_in[2];
    const float* eps    = (const float*)d_in[3];
    const float* emb    = (const float*)d_in[4];
    const float* Wih_f  = (const float*)d_in[5];
    const float* Whh_f  = (const float*)d_in[6];
    const float* b_f    = (const float*)d_in[7];
    const float* Wih_b  = (const float*)d_in[8];
    const float* Whh_b  = (const float*)d_in[9];
    const float* b_b    = (const float*)d_in[10];
    const float* Wm     = (const float*)d_in[11];
    const float* bm     = (const float*)d_in[12];
    const float* Wl     = (const float*)d_in[13];
    const float* bl     = (const float*)d_in[14];
    const float* Wz     = (const float*)d_in[15];
    const float* bz     = (const float*)d_in[16];
    const float* Wi     = (const float*)d_in[17];
    const float* bi     = (const float*)d_in[18];
    const float* Wo     = (const float*)d_in[19];
    const float* bo     = (const float*)d_in[20];
    const float* Wfm    = (const float*)d_in[21];
    const float* bf     = (const float*)d_in[22];
    const float* Wg     = (const float*)d_in[23];
    const float* bg     = (const float*)d_in[24];
    const float* W1     = (const float*)d_in[25];
    const float* b1     = (const float*)d_in[26];
    const float* W2     = (const float*)d_in[27];
    const float* b2     = (const float*)d_in[28];

    float*  ml   = (float*)d_ws;                    // 256K f32
    float*  accs = ml + 1024 * 256;                 // 8 (+pad 64)
    ushort* cenc = (ushort*)(accs + 64);            // 2M bf16
    ushort* cdec = cenc + 2 * 1024 * 1024;          // 1M bf16
    ushort* hA   = cdec + 1024 * 1024;              // 2M
    ushort* hB   = hA + 2 * 1024 * 1024;
    ushort* hdA  = hB + 2 * 1024 * 1024;            // 1M
    ushort* hdB  = hdA + 1024 * 1024;
    ushort* h1A  = hdB + 1024 * 1024;               // 1M
    ushort* h1B  = h1A + 1024 * 1024;
    ushort* zp   = h1B + 1024 * 1024;               // 128K
    ushort* xe   = zp + 1024 * 128;                 // 15*2048*128
    ushort* xd   = xe + 15 * 2048 * 128;            // 15*1024*128
    ushort* Wenc = xd + 15 * 1024 * 128;            // 2*4096*1152
    ushort* Wdec = Wenc + 2 * 4096 * 1152;          // 4096*1152
    ushort* W1p  = Wdec + 4096 * 1152;              // 1024*1280
    ushort* Wml  = W1p + 1024 * 1280;               // 256*2048
    ushort* Wzp  = Wml + 256 * 2048;                // 1024*128
    ushort* W2p  = Wzp + 1024 * 128;                // 128*1024

    init_zero<<<8192, 256, 0, stream>>>(cenc, cdec, hA, accs);
    pack_gates_enc<<<9216, 256, 0, stream>>>(Wih_f, Whh_f, Wih_b, Whh_b, Wenc);
    pack_gates_dec<<<4608, 256, 0, stream>>>(Wi, Wo, Wfm, Wg, Wdec);
    pack_cols<<<1280, 256, 0, stream>>>(W1, 1280, W1p, 1280, 0, 1024, 1280);
    pack_cols<<<256, 256, 0, stream>>>(Wm, 2048, Wml, 2048, 0, L_, 2048);
    pack_cols<<<256, 256, 0, stream>>>(Wl, 2048, Wml + L_ * 2048, 2048, 0, L_, 2048);
    pack_cols<<<128, 256, 0, stream>>>(Wz, L_, Wzp, L_, 0, H_, L_);
    pack_w2<<<128, 256, 0, stream>>>(W2, W2p);
    pack_xenc<<<3840, 256, 0, stream>>>(x_enc, lengths, xe);
    pack_xdec<<<1920, 256, 0, stream>>>(emb, tokens, xd);

    // ---- encoder: grid (32, 32) = 1024 blocks = 4/CU ----
    {
        const ushort* hc = hA; ushort* hn = hB;
        for (int t = 0; t < T_; ++t) {
            gemm_t64<<<dim3(32, 32), 256, 0, stream>>>(
                ALdEnc{ xe + (size_t)t * 2048 * 128, hc, 0 }, WLdEnc{ Wenc },
                EpiEnc{ b_f, b_b, lengths, t, cenc, hc, hn });
            const ushort* tmp = hn; hn = (ushort*)hc; hc = tmp;
        }
        gemm_t64<<<dim3(2, 16), 256, 0, stream>>>(
            ALdHid{ hc, 0 }, WLdPlain{ Wml, 2048 }, EpiStoreF32{ ml, 256 });
    }
    latent_ew<<<512, 256, 0, stream>>>(ml, bm, bl, eps, zp, &accs[3]);
    gemm_t64<<<dim3(8, 16), 256, 0, stream>>>(
        ALdPlain{ zp, 128, 128, 0 }, WLdPlain{ Wzp, 128 }, EpiBiasBf16{ hdA, bz });

    // ---- decoder: grid (41, 16) = 656 blocks; scores(t-1) fused ----
    {
        const ushort* dc = hdA; ushort* dn = hdB;
        for (int t = 0; t < T_; ++t) {
            ushort* h1c = (t & 1) ? h1B : h1A;
            const ushort* h1p = (t & 1) ? h1A : h1B;
            dim3 grid(t == 0 ? 40 : 41, 16);
            gemm_t64<<<grid, 256, 0, stream>>>(
                ALdDec{ xd + (size_t)t * 1024 * 128, dc, zp, h1p, 0 },
                WLdDec{ Wdec, W1p, W2p },
                EpiDec{ bi, bo, bf, bg, b1, b2, cdec, dn, h1c, tokens, lengths, t, accs });
            const ushort* tmp = dn; dn = (ushort*)dc; dc = tmp;
        }
        const ushort* h1p14 = ((T_ - 1) & 1) ? h1B : h1A;  // hid1 written at t=14
        gemm_t64<<<dim3(1, 16), 256, 0, stream>>>(
            ALdDec{ xd, dc, zp, h1p14, 5120 },
            WLdDec{ Wdec, W1p, W2p },
            EpiDec{ bi, bo, bf, bg, b1, b2, cdec, hdB, h1B, tokens, lengths, T_, accs });
    }

    finalize_k<<<1, 64, 0, stream>>>(accs, (float*)d_out);
}

// Round 10
// 1122.979 us; speedup vs baseline: 1.9819x; 1.0382x over previous
//
#include <hip/hip_runtime.h>
#include <math.h>

#define B_ 1024
#define T_ 15
#define E_ 128
#define H_ 1024
#define L_ 128
#define V_ 21

typedef unsigned char u8;
typedef long i64;
typedef __attribute__((ext_vector_type(8))) short bf16x8;
typedef __attribute__((ext_vector_type(4))) float f32x4;

__device__ __forceinline__ float sigf(float x) { return 1.0f / (1.0f + __expf(-x)); }
__device__ __forceinline__ float tanhfast(float x) {
    float t = __expf(-2.0f * fabsf(x));
    float r = (1.0f - t) / (1.0f + t);
    return copysignf(r, x);
}

__device__ __forceinline__ ushort f2bf(float f) {
    unsigned u = __float_as_uint(f);
    u += 0x7fffu + ((u >> 16) & 1u);
    return (ushort)(u >> 16);
}
__device__ __forceinline__ float bf2f(ushort u) {
    return __uint_as_float((unsigned)u << 16);
}

// f32 -> OCP e4m3fn, RNE, saturate to 448
__device__ __forceinline__ u8 f2e4(float x) {
    unsigned u = __float_as_uint(x);
    u8 s = (u >> 24) & 0x80;
    float ax = fminf(fabsf(x), 448.0f);
    unsigned ua = __float_as_uint(ax);
    int e = (int)(ua >> 23) - 127;
    if (e < -6) {                       // denormal target (units of 2^-9) or zero
        int q = (int)rintf(ax * 512.0f);
        return s | (u8)q;
    }
    unsigned m = ua & 0x7FFFFFu;
    unsigned lsb = (m >> 20) & 1u;
    m += 0x7FFFFu + lsb;
    if (m >> 23) { m = 0; e += 1; }
    if (e > 8) return s | 0x7E;
    return s | (u8)(((e + 7) << 3) | (m >> 20));
}

__device__ __forceinline__ void gl_lds16(const void* g, void* l) {
    __builtin_amdgcn_global_load_lds(
        (const __attribute__((address_space(1))) void*)g,
        (__attribute__((address_space(3))) void*)l, 16, 0, 0);
}

// ========== fp8 64x128 MFMA GEMM, BK=64 (two 32B k-slabs), dbuf ==========
// 4 waves (wr|wc), wave 32x64 = acc[2][4] of 16x16x32 fp8. LDS 24 KB, 4 blk/CU.
// LDS layout per buf: A [ch2][64][32B], W [ch2][128][32B]; staged linearly by
// gl_lds (lane l -> row l>>1, byte (l&1)*16; rule #21 both-sides-linear).
// Fragment ds_read_b64: 16 lanes x 32B-stride rows -> 4-way conflict (was 8-way).
// Sync discipline = proven R4/R7/R9: issue STAGE early, __syncthreads drain/iter.
template <class ALd, class WLd, class Epi>
__global__ __launch_bounds__(256, 4) void gemm_f8(ALd al, WLd wl, Epi ep) {
    __shared__ u8 As[2 * 4096];
    __shared__ u8 Ws[2 * 8192];
    const int tid = threadIdx.x;
    const int lane = tid & 63;
    const int w = tid >> 6;
    const int wr = w >> 1, wc = w & 1;
    const int bn = blockIdx.x * 128 + al.bn0;
    const int bm = blockIdx.y * 64;
    const int lrow = lane >> 1;          // 0..31
    const int lcolb = (lane & 1) * 16;   // 0 or 16 (bytes)
    const int K = al.kdim(bn);
    const int nt = K >> 6;

    // wave w owns chunks i = w*3+r; i<4: A (ch=i>>1, rowhalf=i&1); else W (ch=j>>2, rowq=j&3)
    const u8* gp[3];
    u8* ld0[3];
    int bstr[3];
#pragma unroll
    for (int r = 0; r < 3; ++r) {
        const int i = w * 3 + r;
        if (i < 4) {
            ld0[r] = As + (i >> 1) * 2048 + (i & 1) * 1024;
            bstr[r] = 4096;
            gp[r] = al.addr(bn, bm + (i & 1) * 32 + lrow, (i >> 1) * 32 + lcolb);
        } else {
            const int jj = i - 4;
            ld0[r] = Ws + (jj >> 2) * 4096 + (jj & 3) * 1024;
            bstr[r] = 8192;
            gp[r] = wl.addr(bm, bn + (jj & 3) * 32 + lrow, (jj >> 2) * 32 + lcolb);
        }
    }

    auto STAGE = [&](int k0, int buf) {
        const bool relA = al.reloadAt(k0);
        const bool relW = wl.reloadAt(k0);
#pragma unroll
        for (int r = 0; r < 3; ++r) {
            const int i = w * 3 + r;
            if (i < 4) {
                if (relA) gp[r] = al.addr(bn, bm + (i & 1) * 32 + lrow, k0 + (i >> 1) * 32 + lcolb);
            } else {
                const int jj = i - 4;
                if (relW) gp[r] = wl.addr(bm, bn + (jj & 3) * 32 + lrow, k0 + (jj >> 2) * 32 + lcolb);
            }
            gl_lds16(gp[r], ld0[r] + (buf ? bstr[r] : 0));
            gp[r] += 64;
        }
    };

    f32x4 acc[2][4];
#pragma unroll
    for (int m = 0; m < 2; ++m)
#pragma unroll
        for (int n = 0; n < 4; ++n) acc[m][n] = (f32x4)0.0f;

    STAGE(0, 0);
    __syncthreads();

    const int frow = lane & 15, fkb = (lane >> 4) * 8;
    const int aoff = (wr * 32 + frow) * 32 + fkb;
    const int woff = (wc * 64 + frow) * 32 + fkb;

    for (int t = 0; t < nt; ++t) {
        if (t + 1 < nt) STAGE((t + 1) << 6, (t + 1) & 1);
        const u8* ab = As + (t & 1) * 4096;
        const u8* wb = Ws + (t & 1) * 8192;
#pragma unroll
        for (int ch = 0; ch < 2; ++ch) {
            i64 af[2], bw[4];
#pragma unroll
            for (int m = 0; m < 2; ++m) af[m] = *(const i64*)(ab + ch * 2048 + aoff + m * 512);
#pragma unroll
            for (int n = 0; n < 4; ++n) bw[n] = *(const i64*)(wb + ch * 4096 + woff + n * 512);
#pragma unroll
            for (int m = 0; m < 2; ++m)
#pragma unroll
                for (int n = 0; n < 4; ++n)
                    acc[m][n] = __builtin_amdgcn_mfma_f32_16x16x32_fp8_fp8(af[m], bw[n], acc[m][n], 0, 0, 0);
        }
        __syncthreads();
    }
    ep(bm, bn, wr, wc, lane, acc);
}

// ========== bf16 64x128 MFMA GEMM, BK=32 (R9, kept for latent-path GEMMs) ==========
template <class ALd, class WLd, class Epi>
__global__ __launch_bounds__(256, 4) void gemm_t64(ALd al, WLd wl, Epi ep) {
    __shared__ ushort As[2 * 2048];
    __shared__ ushort Ws[2 * 4096];
    const int tid = threadIdx.x;
    const int lane = tid & 63;
    const int w = tid >> 6;
    const int wr = w >> 1, wc = w & 1;
    const int bn = blockIdx.x * 128 + al.bn0;
    const int bm = blockIdx.y * 64;
    const int grow = lane >> 2;
    const int gcol = (lane & 3) * 8;
    const int K = al.kdim(bn);
    const int nt = K >> 5;

    const ushort* gp[3];
    ushort* ld0[3];
    int lstride[3];
    bool isA[3];
#pragma unroll
    for (int r = 0; r < 3; ++r) {
        const int i = w * 3 + r;
        isA[r] = (i < 4);
        ld0[r] = isA[r] ? (As + i * 512) : (Ws + (i - 4) * 512);
        lstride[r] = isA[r] ? 2048 : 4096;
        gp[r] = isA[r] ? al.addr(bn, bm + i * 16 + grow, gcol)
                       : wl.addr(bm, bn + (i - 4) * 16 + grow, gcol);
    }

    auto STAGE = [&](int k0, int buf) {
#pragma unroll
        for (int r = 0; r < 3; ++r) {
            if (isA[r]) {
                if (al.reloadAt(k0))
                    gp[r] = al.addr(bn, bm + (w * 3 + r) * 16 + grow, k0 + gcol);
            } else {
                if (wl.reloadAt(k0))
                    gp[r] = wl.addr(bm, bn + (w * 3 + r - 4) * 16 + grow, k0 + gcol);
            }
            gl_lds16(gp[r], ld0[r] + (buf ? lstride[r] : 0));
            gp[r] += 32;
        }
    };

    f32x4 acc[2][4];
#pragma unroll
    for (int m = 0; m < 2; ++m)
#pragma unroll
        for (int n = 0; n < 4; ++n) acc[m][n] = (f32x4)0.0f;

    STAGE(0, 0);
    __syncthreads();

    const int frow = lane & 15, fk = (lane >> 4) * 8;
    const int foff = (wr * 32 + frow) * 32 + fk;
    const int goff = (wc * 64 + frow) * 32 + fk;

    for (int t = 0; t < nt; ++t) {
        if (t + 1 < nt) STAGE((t + 1) * 32, (t + 1) & 1);
        const ushort* asp = As + (t & 1) * 2048 + foff;
        const ushort* bsp = Ws + (t & 1) * 4096 + goff;
        bf16x8 af[2], bw[4];
#pragma unroll
        for (int m = 0; m < 2; ++m) af[m] = *(const bf16x8*)(asp + m * 512);
#pragma unroll
        for (int n = 0; n < 4; ++n) bw[n] = *(const bf16x8*)(bsp + n * 512);
#pragma unroll
        for (int m = 0; m < 2; ++m)
#pragma unroll
            for (int n = 0; n < 4; ++n)
                acc[m][n] = __builtin_amdgcn_mfma_f32_16x16x32_bf16(af[m], bw[n], acc[m][n], 0, 0, 0);
        __syncthreads();
    }
    ep(bm, bn, wr, wc, lane, acc);
}

// ================= fp8 loaders =================
struct ALdEnc8 {  // rows: dir*1024+b ; cols(bytes): [x_t(128) | h(1024)]
    const u8* xe; const u8* h; int bn0;
    __device__ int kdim(int) const { return 1152; }
    __device__ bool reloadAt(int k) const { return k == 128; }
    __device__ const u8* addr(int, int row, int k) const {
        return (k < 128) ? xe + (size_t)row * 128 + k
                         : h + (size_t)row * 1024 + (k - 128);
    }
};
struct WLdEnc8 {  // [2][4096][1152] gate-interleaved, dir = bm>>10
    const u8* W;
    __device__ bool reloadAt(int) const { return false; }
    __device__ const u8* addr(int bm, int n, int k) const {
        return W + ((size_t)(bm >> 10) * 4096 + n) * 1152 + k;
    }
};
struct ALdDec8 {  // [x_t | h | z]; bn>=5120 -> hid1prev (K=1024)
    const u8* xd; const u8* h; const u8* z; const u8* h1p; int bn0;
    __device__ int kdim(int bn) const {
        return bn < 4096 ? 1152 : (bn < 5120 ? 1280 : 1024);
    }
    __device__ bool reloadAt(int k) const { return k == 128 || k == 1152; }
    __device__ const u8* addr(int bn, int row, int k) const {
        if (bn >= 5120) return h1p + (size_t)row * 1024 + k;
        if (k < 128) return xd + (size_t)row * 128 + k;
        if (k < 1152) return h + (size_t)row * 1024 + (k - 128);
        return z + (size_t)row * 128 + (k - 1152);
    }
};
struct WLdDec8 {
    const u8* Wg4; const u8* W1; const u8* W2p;
    __device__ bool reloadAt(int) const { return false; }
    __device__ const u8* addr(int, int n, int k) const {
        if (n < 4096) return Wg4 + (size_t)n * 1152 + k;
        if (n < 5120) return W1 + (size_t)(n - 4096) * 1280 + k;
        return W2p + (size_t)(n - 5120) * 1024 + k;
    }
};

// ================= bf16 loaders (latent path) =================
struct ALdPlain {
    const ushort* A; int ld; int K; int bn0;
    __device__ int kdim(int) const { return K; }
    __device__ bool reloadAt(int) const { return false; }
    __device__ const ushort* addr(int, int row, int k) const { return A + (size_t)row * ld + k; }
};
struct WLdPlain {
    const ushort* W; int ld;
    __device__ bool reloadAt(int) const { return false; }
    __device__ const ushort* addr(int, int n, int k) const { return W + (size_t)n * ld + k; }
};

// ================= epilogues =================
struct EpiEnc8 {  // fused encoder LSTM cell; frag n = gate n (i,f,g,o)
    const float* b_f; const float* b_b; const int* len; int t;
    ushort* c; const u8* hc8; u8* hn8; ushort* hidp;   // hidp: [b][dir*1024+j] bf16
    __device__ void operator()(int bm, int bn, int wr, int wc, int lane,
                               f32x4 (&acc)[2][4]) const {
        const int j = ((bn >> 6) + wc) * 16 + (lane & 15);
        const int rbase = bm + wr * 32 + ((lane >> 4) << 2);
#pragma unroll
        for (int m = 0; m < 2; ++m) {
#pragma unroll
            for (int r = 0; r < 4; ++r) {
                const int row = rbase + m * 16 + r;
                const int b = row & 1023;
                const int dir = row >> 10;
                const float* bias = dir ? b_b : b_f;
                const size_t o = (size_t)row * 1024 + j;
                if (t < len[b]) {
                    float gi = acc[m][0][r] + bias[j];
                    float gf = acc[m][1][r] + bias[1024 + j];
                    float gg = acc[m][2][r] + bias[2048 + j];
                    float go = acc[m][3][r] + bias[3072 + j];
                    float nc = sigf(gf) * bf2f(c[o]) + sigf(gi) * tanhfast(gg);
                    c[o] = f2bf(nc);
                    float nh = sigf(go) * tanhfast(nc);
                    hn8[o] = f2e4(nh);
                    hidp[(size_t)b * 2048 + dir * 1024 + j] = f2bf(nh);
                } else {
                    hn8[o] = hc8[o];
                }
            }
        }
    }
};

struct EpiDec8 {
    const float *bi, *bo, *bfv, *bg, *b1, *b2;
    ushort* c; u8* hn8; u8* hid1cur;
    const int* tokens; const int* len; int t;
    float* accs;
    __device__ void operator()(int bm, int bn, int wr, int wc, int lane,
                               f32x4 (&acc)[2][4]) const {
        const int rbase = bm + wr * 32 + ((lane >> 4) << 2);
        if (bn < 4096) {            // fused decoder LSTM cell (i,o,f,g)
            const int j = ((bn >> 6) + wc) * 16 + (lane & 15);
#pragma unroll
            for (int m = 0; m < 2; ++m) {
#pragma unroll
                for (int r = 0; r < 4; ++r) {
                    const int b = rbase + m * 16 + r;
                    const size_t o = (size_t)b * 1024 + j;
                    float gi = sigf(acc[m][0][r] + bi[j]);
                    float go = sigf(acc[m][1][r] + bo[j]);
                    float gf = sigf(acc[m][2][r] + bfv[j]);
                    float gg = tanhfast(acc[m][3][r] + bg[j]);
                    float nc = gf * bf2f(c[o]) + gi * gg;
                    c[o] = f2bf(nc);
                    hn8[o] = f2e4(go * tanhfast(nc));
                }
            }
        } else if (bn < 5120) {     // hid1 = relu(ah@W1^T + b1), fp8
            const int cb = (bn - 4096) + wc * 64;
#pragma unroll
            for (int m = 0; m < 2; ++m)
#pragma unroll
                for (int n = 0; n < 4; ++n) {
                    const int col = cb + n * 16 + (lane & 15);
#pragma unroll
                    for (int r = 0; r < 4; ++r)
                        hid1cur[(size_t)(rbase + m * 16 + r) * 1024 + col] =
                            f2e4(fmaxf(acc[m][n][r] + b1[col], 0.0f));
                }
        } else {                    // scores(t-1): CE/argmax, wave-parallel
            if (wc != 0) return;
            const int ts = t - 1;
            const int col0 = lane & 15;
            const bool v1ok = col0 < (V_ - 16);
            const float b2v0 = b2[col0];
            const float b2v1 = v1ok ? b2[16 + col0] : 0.0f;
            float ce_loc = 0.f, cor_loc = 0.f, msk_loc = 0.f;
#pragma unroll
            for (int m = 0; m < 2; ++m) {
#pragma unroll
                for (int r = 0; r < 4; ++r) {
                    const int b = rbase + m * 16 + r;
                    const int lb = len[b];
                    float v0 = acc[m][0][r] + b2v0;
                    float v1 = v1ok ? (acc[m][1][r] + b2v1) : -1e30f;
                    float mv; int mi;
                    if (v1 > v0) { mv = v1; mi = 16 + col0; } else { mv = v0; mi = col0; }
#pragma unroll
                    for (int s = 1; s < 16; s <<= 1) {
                        float ov = __shfl_xor(mv, s);
                        int oi = __shfl_xor(mi, s);
                        if (ov > mv || (ov == mv && oi < mi)) { mv = ov; mi = oi; }
                    }
                    float se = expf(v0 - mv) + (v1ok ? expf(v1 - mv) : 0.0f);
#pragma unroll
                    for (int s = 1; s < 16; s <<= 1) se += __shfl_xor(se, s);
                    float lse = mv + logf(se);
                    int tgt = (ts < lb) ? tokens[b * T_ + ts] : 0;
                    int srcl = (lane & 48) | (tgt & 15);
                    float sv0 = __shfl(v0, srcl);
                    float sv1 = __shfl(v1, srcl);
                    float stgt = (tgt < 16) ? sv0 : sv1;
                    if (ts <= lb && col0 == 0) {
                        ce_loc += lse - stgt;
                        cor_loc += (mi == tgt) ? 1.0f : 0.0f;
                        msk_loc += 1.0f;
                    }
                }
            }
            float ce = __shfl(ce_loc, 0) + __shfl(ce_loc, 16) + __shfl(ce_loc, 32) + __shfl(ce_loc, 48);
            float co = __shfl(cor_loc, 0) + __shfl(cor_loc, 16) + __shfl(cor_loc, 32) + __shfl(cor_loc, 48);
            float mk = __shfl(msk_loc, 0) + __shfl(msk_loc, 16) + __shfl(msk_loc, 32) + __shfl(msk_loc, 48);
            if (lane == 0) {
                atomicAdd(&accs[0], ce);
                atomicAdd(&accs[1], co);
                atomicAdd(&accs[2], mk);
            }
        }
    }
};

struct EpiStoreF32 {
    float* out; int ldc;
    __device__ void operator()(int bm, int bn, int wr, int wc, int lane,
                               f32x4 (&acc)[2][4]) const {
        const int rbase = bm + wr * 32 + ((lane >> 4) << 2);
        const int cbase = bn + wc * 64 + (lane & 15);
#pragma unroll
        for (int m = 0; m < 2; ++m)
#pragma unroll
            for (int n = 0; n < 4; ++n)
#pragma unroll
                for (int r = 0; r < 4; ++r)
                    out[(size_t)(rbase + m * 16 + r) * ldc + cbase + n * 16] = acc[m][n][r];
    }
};
struct EpiBiasF8 {   // h0 = z@Wz^T + bz -> fp8
    u8* out; const float* bias;
    __device__ void operator()(int bm, int bn, int wr, int wc, int lane,
                               f32x4 (&acc)[2][4]) const {
        const int rbase = bm + wr * 32 + ((lane >> 4) << 2);
        const int cbase = bn + wc * 64 + (lane & 15);
#pragma unroll
        for (int m = 0; m < 2; ++m)
#pragma unroll
            for (int n = 0; n < 4; ++n) {
                const int col = cbase + n * 16;
#pragma unroll
                for (int r = 0; r < 4; ++r)
                    out[(size_t)(rbase + m * 16 + r) * 1024 + col] = f2e4(acc[m][n][r] + bias[col]);
            }
    }
};

// ================= packing / elementwise =================
__global__ void pack_cols(const float* __restrict__ src, int src_ld,
                          ushort* __restrict__ dst, int dst_ld, int dcol0,
                          int rows, int cols) {
    int i = blockIdx.x * 256 + threadIdx.x;
    int c4cnt = cols >> 2;
    if (i >= rows * c4cnt) return;
    int r = i / c4cnt, c4 = (i - r * c4cnt) * 4;
    float4 v = *(const float4*)(src + (size_t)r * src_ld + c4);
    ushort4 o = { f2bf(v.x), f2bf(v.y), f2bf(v.z), f2bf(v.w) };
    *(ushort4*)(dst + (size_t)r * dst_ld + dcol0 + c4) = o;
}

__global__ void pack_cols8(const float* __restrict__ src, int src_ld,
                           u8* __restrict__ dst, int dst_ld, int rows, int cols) {
    int i = blockIdx.x * 256 + threadIdx.x;
    int c4cnt = cols >> 2;
    if (i >= rows * c4cnt) return;
    int r = i / c4cnt, c4 = (i - r * c4cnt) * 4;
    float4 v = *(const float4*)(src + (size_t)r * src_ld + c4);
    unsigned o = f2e4(v.x) | ((unsigned)f2e4(v.y) << 8) |
                 ((unsigned)f2e4(v.z) << 16) | ((unsigned)f2e4(v.w) << 24);
    *(unsigned*)(dst + (size_t)r * dst_ld + c4) = o;
}

__global__ void pack_gates_enc8(const float* __restrict__ Wih_f, const float* __restrict__ Whh_f,
                                const float* __restrict__ Wih_b, const float* __restrict__ Whh_b,
                                u8* __restrict__ dst) {
    int i = blockIdx.x * 256 + threadIdx.x;   // 2*4096*288
    if (i >= 2 * 4096 * 288) return;
    int c4 = (i % 288) * 4;
    int p = (i / 288) & 4095;
    int dir = i / (288 * 4096);
    int j = ((p >> 6) << 4) + (p & 15);
    int g = (p >> 4) & 3;
    int srow = g * 1024 + j;
    float4 v;
    if (c4 < 128) {
        const float* s = dir ? Wih_b : Wih_f;
        v = *(const float4*)(s + (size_t)srow * 128 + c4);
    } else {
        const float* s = dir ? Whh_b : Whh_f;
        v = *(const float4*)(s + (size_t)srow * 1024 + (c4 - 128));
    }
    unsigned o = f2e4(v.x) | ((unsigned)f2e4(v.y) << 8) |
                 ((unsigned)f2e4(v.z) << 16) | ((unsigned)f2e4(v.w) << 24);
    *(unsigned*)(dst + ((size_t)dir * 4096 + p) * 1152 + c4) = o;
}

__global__ void pack_gates_dec8(const float* __restrict__ Wi, const float* __restrict__ Wo,
                                const float* __restrict__ Wf, const float* __restrict__ Wg,
                                u8* __restrict__ dst) {
    int i = blockIdx.x * 256 + threadIdx.x;   // 4096*288
    if (i >= 4096 * 288) return;
    int c4 = (i % 288) * 4;
    int p = i / 288;
    int j = ((p >> 6) << 4) + (p & 15);
    int g = (p >> 4) & 3;
    const float* s = (g == 0) ? Wi : (g == 1) ? Wo : (g == 2) ? Wf : Wg;
    float4 v = *(const float4*)(s + (size_t)j * 1152 + c4);
    unsigned o = f2e4(v.x) | ((unsigned)f2e4(v.y) << 8) |
                 ((unsigned)f2e4(v.z) << 16) | ((unsigned)f2e4(v.w) << 24);
    *(unsigned*)(dst + (size_t)p * 1152 + c4) = o;
}

__global__ void pack_w28(const float* __restrict__ W2, u8* __restrict__ dst) {
    int i = blockIdx.x * 256 + threadIdx.x;   // 128*256
    if (i >= 128 * 256) return;
    int r = i >> 8, c4 = (i & 255) * 4;
    unsigned o = 0;
    if (r < V_) {
        float4 v = *(const float4*)(W2 + (size_t)r * 1024 + c4);
        o = f2e4(v.x) | ((unsigned)f2e4(v.y) << 8) |
            ((unsigned)f2e4(v.z) << 16) | ((unsigned)f2e4(v.w) << 24);
    }
    *(unsigned*)(dst + (size_t)r * 1024 + c4) = o;
}

__global__ void pack_xenc8(const float* __restrict__ xenc, const int* __restrict__ len,
                           u8* __restrict__ xe) {
    int i = blockIdx.x * 256 + threadIdx.x;   // 15*2048*32
    if (i >= 15 * 2048 * 32) return;
    int c4 = (i & 31) * 4;
    int r = (i >> 5) & 2047;
    int t = i >> 16;
    int dir = r >> 10, b = r & 1023;
    int tt = t;
    if (dir) {
        int ri = len[b] - 1 - t;
        tt = ri < 0 ? 0 : (ri > T_ - 1 ? T_ - 1 : ri);
    }
    float4 v = *(const float4*)(xenc + ((size_t)b * T_ + tt) * 128 + c4);
    unsigned o = f2e4(v.x) | ((unsigned)f2e4(v.y) << 8) |
                 ((unsigned)f2e4(v.z) << 16) | ((unsigned)f2e4(v.w) << 24);
    *(unsigned*)(xe + ((size_t)t * 2048 + r) * 128 + c4) = o;
}

__global__ void pack_xdec8(const float* __restrict__ emb, const int* __restrict__ tokens,
                           u8* __restrict__ xd) {
    int i = blockIdx.x * 256 + threadIdx.x;   // 15*1024*32
    if (i >= 15 * 1024 * 32) return;
    int c4 = (i & 31) * 4;
    int b = (i >> 5) & 1023;
    int t = i >> 15;
    unsigned o = 0;
    if (t > 0) {
        int tok = tokens[(size_t)b * T_ + (t - 1)];
        float4 v = *(const float4*)(emb + (size_t)tok * 128 + c4);
        o = f2e4(v.x) | ((unsigned)f2e4(v.y) << 8) |
            ((unsigned)f2e4(v.z) << 16) | ((unsigned)f2e4(v.w) << 24);
    }
    *(unsigned*)(xd + ((size_t)t * 1024 + b) * 128 + c4) = o;
}

__global__ void init_zero(ushort* cenc, ushort* cdec, u8* h8A, float* accs) {
    int i = blockIdx.x * 256 + threadIdx.x;   // 2M threads
    if (i < 2 * 1024 * 1024) { cenc[i] = 0; h8A[i] = 0; }
    if (i < 1024 * 1024) cdec[i] = 0;
    if (i < 8) accs[i] = 0.0f;
}

__global__ void latent_ew(const float* __restrict__ ml, const float* __restrict__ bmv,
                          const float* __restrict__ blv, const float* __restrict__ eps,
                          ushort* __restrict__ zb, u8* __restrict__ z8,
                          float* __restrict__ klacc) {
    int idx = blockIdx.x * 256 + threadIdx.x;
    int b = idx >> 7, l = idx & (L_ - 1);
    float mean = ml[(size_t)b * 256 + l] + bmv[l];
    float logv = ml[(size_t)b * 256 + L_ + l] + blv[l];
    float zv = eps[idx] * expf(0.5f * logv) + mean;
    zb[idx] = f2bf(zv);
    z8[idx] = f2e4(zv);
    float part = 1.0f + logv - mean * mean - expf(logv);
    for (int off = 32; off; off >>= 1) part += __shfl_down(part, off);
    __shared__ float s[4];
    int lane = threadIdx.x & 63, wv = threadIdx.x >> 6;
    if (lane == 0) s[wv] = part;
    __syncthreads();
    if (threadIdx.x == 0) atomicAdd(klacc, s[0] + s[1] + s[2] + s[3]);
}

__global__ void finalize_k(const float* accs, float* out) {
    if (threadIdx.x == 0 && blockIdx.x == 0) {
        float kl = -0.5f * accs[3] / (float)B_;
        float amino = accs[0] / (float)B_;
        out[0] = amino + 0.1f * kl;
        out[1] = amino;
        out[2] = kl;
        out[3] = accs[1] / accs[2];
    }
}

// ================= host =================
extern "C" void kernel_launch(void* const* d_in, const int* in_sizes, int n_in,
                              void* d_out, int out_size, void* d_ws, size_t ws_size,
                              hipStream_t stream) {
    (void)in_sizes; (void)n_in; (void)out_size; (void)ws_size;
    const float* x_enc  = (const float*)d_in[0];
    const int*   tokens = (const int*)d_in[1];
    const int*   lengths= (const int*)d_in[2];
    const float* eps    = (const float*)d_in[3];
    const float* emb    = (const float*)d_in[4];
    const float* Wih_f  = (const float*)d_in[5];
    const float* Whh_f  = (const float*)d_in[6];
    const float* b_f    = (const float*)d_in[7];
    const float* Wih_b  = (const float*)d_in[8];
    const float* Whh_b  = (const float*)d_in[9];
    const float* b_b    = (const float*)d_in[10];
    const float* Wm     = (const float*)d_in[11];
    const float* bm     = (const float*)d_in[12];
    const float* Wl     = (const float*)d_in[13];
    const float* bl     = (const float*)d_in[14];
    const float* Wz     = (const float*)d_in[15];
    const float* bz     = (const float*)d_in[16];
    const float* Wi     = (const float*)d_in[17];
    const float* bi     = (const float*)d_in[18];
    const float* Wo     = (const float*)d_in[19];
    const float* bo     = (const float*)d_in[20];
    const float* Wfm    = (const float*)d_in[21];
    const float* bf     = (const float*)d_in[22];
    const float* Wg     = (const float*)d_in[23];
    const float* bg     = (const float*)d_in[24];
    const float* W1     = (const float*)d_in[25];
    const float* b1     = (const float*)d_in[26];
    const float* W2     = (const float*)d_in[27];
    const float* b2     = (const float*)d_in[28];

    float*  ml   = (float*)d_ws;                       // 262144 f32
    float*  accs = ml + 262144;                        // 64
    ushort* cenc = (ushort*)(accs + 64);               // 2M
    ushort* cdec = cenc + 2 * 1024 * 1024;             // 1M
    ushort* hidp = cdec + 1024 * 1024;                 // 1024*2048
    ushort* Wml  = hidp + 2 * 1024 * 1024;             // 256*2048
    ushort* Wzp  = Wml + 256 * 2048;                   // 1024*128
    ushort* zb   = Wzp + 1024 * 128;                   // 1024*128
    u8* h8A  = (u8*)(zb + 1024 * 128);                 // 2M B
    u8* h8B  = h8A + 2 * 1024 * 1024;
    u8* hd8A = h8B + 2 * 1024 * 1024;                  // 1M B
    u8* hd8B = hd8A + 1024 * 1024;
    u8* h18A = hd8B + 1024 * 1024;                     // 1M B
    u8* h18B = h18A + 1024 * 1024;
    u8* z8   = h18B + 1024 * 1024;                     // 128K B
    u8* xe8  = z8 + 1024 * 128;                        // 15*2048*128
    u8* xd8  = xe8 + 15 * 2048 * 128;                  // 15*1024*128
    u8* Wenc8= xd8 + 15 * 1024 * 128;                  // 2*4096*1152
    u8* Wdec8= Wenc8 + 2 * 4096 * 1152;                // 4096*1152
    u8* W1p8 = Wdec8 + 4096 * 1152;                    // 1024*1280
    u8* W2p8 = W1p8 + 1024 * 1280;                     // 128*1024

    init_zero<<<8192, 256, 0, stream>>>(cenc, cdec, h8A, accs);
    pack_gates_enc8<<<9216, 256, 0, stream>>>(Wih_f, Whh_f, Wih_b, Whh_b, Wenc8);
    pack_gates_dec8<<<4608, 256, 0, stream>>>(Wi, Wo, Wfm, Wg, Wdec8);
    pack_cols8<<<1280, 256, 0, stream>>>(W1, 1280, W1p8, 1280, 1024, 1280);
    pack_cols<<<256, 256, 0, stream>>>(Wm, 2048, Wml, 2048, 0, L_, 2048);
    pack_cols<<<256, 256, 0, stream>>>(Wl, 2048, Wml + L_ * 2048, 2048, 0, L_, 2048);
    pack_cols<<<128, 256, 0, stream>>>(Wz, L_, Wzp, L_, 0, H_, L_);
    pack_w28<<<128, 256, 0, stream>>>(W2, W2p8);
    pack_xenc8<<<3840, 256, 0, stream>>>(x_enc, lengths, xe8);
    pack_xdec8<<<1920, 256, 0, stream>>>(emb, tokens, xd8);

    // ---- encoder: fp8, grid (32, 32) = 1024 blocks = 4/CU ----
    {
        const u8* hc = h8A; u8* hn = h8B;
        for (int t = 0; t < T_; ++t) {
            gemm_f8<<<dim3(32, 32), 256, 0, stream>>>(
                ALdEnc8{ xe8 + (size_t)t * 2048 * 128, hc, 0 }, WLdEnc8{ Wenc8 },
                EpiEnc8{ b_f, b_b, lengths, t, cenc, hc, hn, hidp });
            const u8* tmp = hn; hn = (u8*)hc; hc = tmp;
        }
    }
    // ---- latents (bf16 path): [mean|logv] = hidp @ Wml^T ----
    gemm_t64<<<dim3(2, 16), 256, 0, stream>>>(
        ALdPlain{ hidp, 2048, 2048, 0 }, WLdPlain{ Wml, 2048 }, EpiStoreF32{ ml, 256 });
    latent_ew<<<512, 256, 0, stream>>>(ml, bm, bl, eps, zb, z8, &accs[3]);
    gemm_t64<<<dim3(8, 16), 256, 0, stream>>>(
        ALdPlain{ zb, 128, 128, 0 }, WLdPlain{ Wzp, 128 }, EpiBiasF8{ hd8A, bz });

    // ---- decoder: fp8, scores(t-1) fused as extra bn segment ----
    {
        const u8* dc = hd8A; u8* dn = hd8B;
        for (int t = 0; t < T_; ++t) {
            u8* h1c = (t & 1) ? h18B : h18A;
            const u8* h1p = (t & 1) ? h18A : h18B;
            dim3 grid(t == 0 ? 40 : 41, 16);
            gemm_f8<<<grid, 256, 0, stream>>>(
                ALdDec8{ xd8 + (size_t)t * 1024 * 128, dc, z8, h1p, 0 },
                WLdDec8{ Wdec8, W1p8, W2p8 },
                EpiDec8{ bi, bo, bf, bg, b1, b2, cdec, dn, h1c, tokens, lengths, t, accs });
            const u8* tmp = dn; dn = (u8*)dc; dc = tmp;
        }
        // trailing scores for t=14 (hid1 written at t=14 -> h18A)
        gemm_f8<<<dim3(1, 16), 256, 0, stream>>>(
            ALdDec8{ xd8, dc, z8, h18A, 5120 },
            WLdDec8{ Wdec8, W1p8, W2p8 },
            EpiDec8{ bi, bo, bf, bg, b1, b2, cdec, hd8B, h18B, tokens, lengths, T_, accs });
    }

    finalize_k<<<1, 64, 0, stream>>>(accs, (float*)d_out);
}